// Round 6
// baseline (719.657 us; speedup 1.0000x reference)
//
#include <hip/hip_runtime.h>
#include <math.h>

#define HW 65536
#define TH_ 0.024543692606170259f  // 2*pi/256

typedef __attribute__((ext_vector_type(8))) short bf16x8;
typedef __attribute__((ext_vector_type(4))) float f32x4;

// Fast gelu: Abramowitz-Stegun 7.1.26 erf, |abs err| ~3e-7.
__device__ __forceinline__ float gelu_f(float v){
    float u = fabsf(v)*0.7071067811865476f;
    float t = __builtin_amdgcn_rcpf(fmaf(0.3275911f, u, 1.0f));
    float p = t*fmaf(t, fmaf(t, fmaf(t, fmaf(t, 1.061405429f, -1.453152027f),
                     1.421413741f), -0.284496736f), 0.254829592f);
    float e = __expf(-u*u);
    float erfu = fmaf(-p, e, 1.0f);
    float er = copysignf(erfu, v);
    return 0.5f*v*(1.0f+er);
}

__device__ __forceinline__ short f2bf(float f){
    union { float f; unsigned u; } v; v.f = f;
    unsigned r = (v.u + 0x7FFF + ((v.u >> 16) & 1)) >> 16;   // RNE
    return (short)r;
}
__device__ __forceinline__ float bf2f(short s){
    union { float f; unsigned u; } v; v.u = ((unsigned)(unsigned short)s) << 16;
    return v.f;
}

// v_cvt_pk_bf16_f32: D.lo = bf16(S0), D.hi = bf16(S1)
__device__ __forceinline__ unsigned cvt_pk_bf16(float lo, float hi){
    unsigned r;
    asm("v_cvt_pk_bf16_f32 %0, %1, %2" : "=v"(r) : "v"(lo), "v"(hi));
    return r;
}

union U8 { bf16x8 v; unsigned u[4]; };

// split 8 floats -> hi/lo bf16x8 using packed converts
__device__ __forceinline__ void split8(const float* f, bf16x8& H, bf16x8& L){
    U8 h, l;
    #pragma unroll
    for (int p=0;p<4;++p){
        float a = f[2*p], b = f[2*p+1];
        unsigned hp = cvt_pk_bf16(a, b);
        union { unsigned u; float fl; } ua, ub;
        ua.u = hp << 16; ub.u = hp & 0xffff0000u;
        h.u[p] = hp;
        l.u[p] = cvt_pk_bf16(a - ua.fl, b - ub.fl);
    }
    H = h.v; L = l.v;
}

// GH[h] = sum_{ky<16} e^{-2pi i ky h /256}
__global__ void k_tables(float* __restrict__ GH){
    int h = threadIdx.x;
    double gr = 0.0, gi = 0.0;
    for (int ky=0; ky<16; ++ky){
        double a = -2.0*3.14159265358979323846*(double)(ky*h)/256.0;
        gr += cos(a); gi += sin(a);
    }
    GH[2*h] = (float)gr; GH[2*h+1] = (float)gi;
}

// Precompute split-bf16 W1 fragments for k_heads.
__global__ __launch_bounds__(256) void k_prepW(const float* __restrict__ fw1, const float* __restrict__ qw1,
                                               float* __restrict__ Wf){
    int t = blockIdx.x*256 + threadIdx.x;       // 1024 total
    int lane = t & 63, ks = (t>>6)&1, n = (t>>7)&3, ph = (t>>9)&1;
    int l15 = lane & 15, lg = lane >> 4;
    const float* w1p = ph ? qw1 : fw1;
    int oc = n*16 + l15;
    U8 h, l;
    #pragma unroll
    for (int p=0;p<4;++p){
        float a = w1p[oc*64 + ks*32 + lg*8 + 2*p];
        float b = w1p[oc*64 + ks*32 + lg*8 + 2*p+1];
        short ha = f2bf(a), hb = f2bf(b);
        h.u[p] = ((unsigned)(unsigned short)ha) | (((unsigned)(unsigned short)hb)<<16);
        short la = f2bf(a - bf2f(ha)), lb = f2bf(b - bf2f(hb));
        l.u[p] = ((unsigned)(unsigned short)la) | (((unsigned)(unsigned short)lb)<<16);
    }
    int idx = ((ph*4+n)*2+ks)*64 + lane;
    ((bf16x8*)Wf)[idx] = h.v;
    ((bf16x8*)Wf)[1024 + idx] = l.v;
}

// x[b,c,hw] = gelu(sum_i lw[c,i]*state[b,i,hw] + lb[c])
__global__ __launch_bounds__(256) void k_lift(const float* __restrict__ st, const float* __restrict__ lw,
                                              const float* __restrict__ lb, float* __restrict__ x){
    int p = blockIdx.x*256 + threadIdx.x;
    int b = p >> 16, hw = p & (HW-1);
    float s0 = st[(b*3+0)*HW + hw];
    float s1 = st[(b*3+1)*HW + hw];
    float s2 = st[(b*3+2)*HW + hw];
    float* xp = x + (size_t)b*64*HW + hw;
    for (int c=0;c<64;++c){
        float v = fmaf(lw[c*3], s0, fmaf(lw[c*3+1], s1, fmaf(lw[c*3+2], s2, lb[c])));
        xp[(size_t)c*HW] = gelu_f(v);
    }
}

// Layer-0 analysis (reads x)
__global__ __launch_bounds__(256) void k_analysis(const float* __restrict__ x, const float* __restrict__ GH,
                                                  float* __restrict__ S){
    int b = blockIdx.x >> 6, i = blockIdx.x & 63;
    int w = threadIdx.x;
    const float* xp = x + ((size_t)(b*64+i))*HW + w;
    float Tr = 0.f, Ti = 0.f;
    #pragma unroll 4
    for (int h=0; h<256; ++h){
        float v = xp[h*256];
        Tr = fmaf(GH[2*h],   v, Tr);
        Ti = fmaf(GH[2*h+1], v, Ti);
    }
    float c1, s1; sincosf((float)w * TH_, &s1, &c1);
    float Sr[16], Si[16];
    float ck = 1.f, sk = 0.f;
    #pragma unroll
    for (int k=0;k<16;++k){
        Sr[k] = Tr*ck + Ti*sk;     // T * e^{-i th k w}
        Si[k] = Ti*ck - Tr*sk;
        float nc = ck*c1 - sk*s1;
        sk = ck*s1 + sk*c1;
        ck = nc;
    }
    #pragma unroll
    for (int k=0;k<16;++k){
        #pragma unroll
        for (int off=32; off; off>>=1){
            Sr[k] += __shfl_xor(Sr[k], off, 64);
            Si[k] += __shfl_xor(Si[k], off, 64);
        }
    }
    __shared__ float red[4][32];
    int wv = threadIdx.x >> 6, ln = threadIdx.x & 63;
    if (ln == 0){
        #pragma unroll
        for (int k=0;k<16;++k){ red[wv][2*k] = Sr[k]; red[wv][2*k+1] = Si[k]; }
    }
    __syncthreads();
    if (threadIdx.x < 32){
        float v = red[0][threadIdx.x]+red[1][threadIdx.x]+red[2][threadIdx.x]+red[3][threadIdx.x];
        S[(b*64+i)*32 + threadIdx.x] = v * (1.0f/256.0f);
    }
}

// Layers 1-3: analysis from fused T[b,i,w]
__global__ __launch_bounds__(256) void k_analysisT(const float* __restrict__ T, float* __restrict__ S){
    int bi = blockIdx.x;               // b*64+i
    int w = threadIdx.x;
    float2 t = ((const float2*)T)[bi*256 + w];
    float Tr = t.x, Ti = t.y;
    float c1, s1; sincosf((float)w * TH_, &s1, &c1);
    float Sr[16], Si[16];
    float ck = 1.f, sk = 0.f;
    #pragma unroll
    for (int k=0;k<16;++k){
        Sr[k] = Tr*ck + Ti*sk;
        Si[k] = Ti*ck - Tr*sk;
        float nc = ck*c1 - sk*s1;
        sk = ck*s1 + sk*c1;
        ck = nc;
    }
    #pragma unroll
    for (int k=0;k<16;++k){
        #pragma unroll
        for (int off=32; off; off>>=1){
            Sr[k] += __shfl_xor(Sr[k], off, 64);
            Si[k] += __shfl_xor(Si[k], off, 64);
        }
    }
    __shared__ float red[4][32];
    int wv = threadIdx.x >> 6, ln = threadIdx.x & 63;
    if (ln == 0){
        #pragma unroll
        for (int k=0;k<16;++k){ red[wv][2*k] = Sr[k]; red[wv][2*k+1] = Si[k]; }
    }
    __syncthreads();
    if (threadIdx.x < 32){
        float v = red[0][threadIdx.x]+red[1][threadIdx.x]+red[2][threadIdx.x]+red[3][threadIdx.x];
        S[bi*32 + threadIdx.x] = v * (1.0f/256.0f);
    }
}

// A[b,j,km] = sum_i S[b,i,k] * (wr + i wi)[i,j,km]
__global__ __launch_bounds__(256) void k_mixA(const float* __restrict__ S, const float* __restrict__ wr,
                                              const float* __restrict__ wi, float* __restrict__ A){
    int j = blockIdx.x >> 3, b = blockIdx.x & 7;
    __shared__ float sS[2048];
    for (int t=threadIdx.x; t<2048; t+=256) sS[t] = S[b*2048 + t];
    __syncthreads();
    int km = threadIdx.x, k = km >> 4;
    float ar = 0.f, ai = 0.f;
    const float* wrp = wr + j*256 + km;
    const float* wip = wi + j*256 + km;
    #pragma unroll 4
    for (int i=0;i<64;++i){
        float wrv = wrp[i*16384];
        float wiv = wip[i*16384];
        float2 sv = ((const float2*)sS)[i*16 + k];
        ar += sv.x*wrv - sv.y*wiv;
        ai += sv.x*wiv + sv.y*wrv;
    }
    ((float2*)A)[(b*64 + j)*256 + km] = make_float2(ar, ai);
}

// c = sum_j pw[o,j]*A[b,j,km]; Parseval stats; CS = c * inv_sigma * alpha(m) / 256
__global__ __launch_bounds__(256) void k_mixB(const float* __restrict__ A, const float* __restrict__ pw,
                                              float* __restrict__ CS){
    int b = blockIdx.x >> 6, o = blockIdx.x & 63;
    int km = threadIdx.x, m = km & 15;
    const float2* Ap = (const float2*)A + b*64*256 + km;
    const float* pwp = pw + o*64;
    float cr=0.f, ci=0.f;
    #pragma unroll 4
    for (int j=0;j<64;++j){
        float p = pwp[j];
        float2 a = Ap[j*256];
        cr = fmaf(p, a.x, cr);
        ci = fmaf(p, a.y, ci);
    }
    float aw = (m==0)? 1.f : 4.f;          // alpha(m)^2
    float s = (km==0)? 0.f : aw*(cr*cr + ci*ci);
    #pragma unroll
    for (int off=32; off; off>>=1) s += __shfl_xor(s, off, 64);
    __shared__ float rsum[4];
    __shared__ float sinv;
    if ((threadIdx.x & 63) == 0) rsum[threadIdx.x>>6] = s;
    __syncthreads();
    if (threadIdx.x == 0){
        float var = (rsum[0]+rsum[1]+rsum[2]+rsum[3]) * (1.0f/131072.0f); // /(2*H*W)
        sinv = rsqrtf(var + 1e-5f);
    }
    __syncthreads();
    float alpha = (m==0)? 1.f : 2.f;
    float sc = sinv * alpha * (1.0f/256.0f);
    if (km == 0) cr = 0.f;                 // remove mean (DC real part)
    ((float2*)CS)[blockIdx.x*256 + km] = make_float2(cr*sc, ci*sc);
}

// x += gelu(irfft-ish synth); LDS-shared V; optional T-emit.
template<bool EMIT_T>
__global__ __launch_bounds__(256) void k_synth(const float* __restrict__ CS, float* __restrict__ x,
                                               const float* __restrict__ GH, float* __restrict__ T){
    int bo = blockIdx.x >> 2, wt = blockIdx.x & 3;
    int lane = threadIdx.x & 63, wv = threadIdx.x >> 6;
    int w = wt*64 + lane;
    __shared__ float sGH[512];
    __shared__ float2 sV[16][64];
    if (EMIT_T){
        sGH[threadIdx.x] = GH[threadIdx.x];
        sGH[256+threadIdx.x] = GH[256+threadIdx.x];
    }
    const float2* cs = (const float2*)CS + bo*256;
    {   // phase A: thread computes V[k] for k in [4*wv, 4*wv+4)
        float Vr[4] = {0.f,0.f,0.f,0.f}, Vi[4] = {0.f,0.f,0.f,0.f};
        float stepc, steps; sincosf((float)w*TH_, &steps, &stepc);
        float pc = 1.f, ps = 0.f;          // e^{+i m th w}
        for (int m=0;m<16;++m){
            #pragma unroll
            for (int kk=0;kk<4;++kk){
                float2 a = cs[(wv*4+kk)*16 + m];
                Vr[kk] += a.x*pc - a.y*ps;
                Vi[kk] += a.x*ps + a.y*pc;
            }
            float nc = pc*stepc - ps*steps;
            ps = pc*steps + ps*stepc;
            pc = nc;
        }
        #pragma unroll
        for (int kk=0;kk<4;++kk) sV[wv*4+kk][lane] = make_float2(Vr[kk], Vi[kk]);
    }
    __syncthreads();
    int h0 = wv*16;
    float rc[16], rs[16], qr[16], qi[16];
    #pragma unroll
    for (int k=0;k<16;++k){
        float2 v = sV[k][lane];
        sincosf((float)k*TH_, &rs[k], &rc[k]);
        float c0, s0; sincosf((float)(k*h0)*TH_, &s0, &c0);
        qr[k] = v.x*c0 - v.y*s0;       // q = V * e^{+i th k h0}
        qi[k] = v.x*s0 + v.y*c0;
    }
    float* xp = x + ((size_t)bo << 16);
    float Tr = 0.f, Ti = 0.f;
    for (int i=0;i<16;++i){
        float y0=0.f,y1=0.f,y2=0.f,y3=0.f;
        #pragma unroll
        for (int k=0;k<16;++k){
            float re = qr[k], im = qi[k];
            y0 += re;                                   // h
            if ((k&3)==0)      { y1 += re; y2 += re; y3 += re; }   // *i^k, *(-1)^k, *(-i)^k
            else if ((k&3)==1) { y1 -= im; y2 -= re; y3 += im; }
            else if ((k&3)==2) { y1 -= re; y2 += re; y3 -= re; }
            else               { y1 += im; y2 -= re; y3 -= im; }
        }
        #pragma unroll
        for (int k=1;k<16;++k){
            float nr = qr[k]*rc[k] - qi[k]*rs[k];
            qi[k]    = qr[k]*rs[k] + qi[k]*rc[k];
            qr[k] = nr;
        }
        int p0 = (h0+i)*256 + w;
        float x0 = xp[p0], x1 = xp[p0+16384], x2 = xp[p0+32768], x3 = xp[p0+49152];
        float n0 = gelu_f(y0) + x0;
        float n1 = gelu_f(y1) + x1;
        float n2 = gelu_f(y2) + x2;
        float n3 = gelu_f(y3) + x3;
        xp[p0]       = n0;
        xp[p0+16384] = n1;
        xp[p0+32768] = n2;
        xp[p0+49152] = n3;
        if (EMIT_T){
            int h = h0+i;
            Tr = fmaf(sGH[2*h],     n0, Tr);  Ti = fmaf(sGH[2*h+1],     n0, Ti);
            Tr = fmaf(sGH[2*h+128], n1, Tr);  Ti = fmaf(sGH[2*h+129],   n1, Ti);
            Tr = fmaf(sGH[2*h+256], n2, Tr);  Ti = fmaf(sGH[2*h+257],   n2, Ti);
            Tr = fmaf(sGH[2*h+384], n3, Tr);  Ti = fmaf(sGH[2*h+385],   n3, Ti);
        }
    }
    if (EMIT_T){
        __shared__ float2 tpart[4][64];
        tpart[wv][lane] = make_float2(Tr, Ti);
        __syncthreads();
        if (wv == 0){
            float2 a = tpart[0][lane], b2 = tpart[1][lane];
            float2 c = tpart[2][lane], d = tpart[3][lane];
            ((float2*)T)[bo*256 + w] = make_float2(a.x+b2.x+c.x+d.x, a.y+b2.y+c.y+d.y);
        }
    }
}

// MFMA heads; ph=1 (polarization) writes final outputs directly (k_final folded in).
// __launch_bounds__(256,4): 4 blocks/CU -> VGPR<=128 (R5 hit the 132-VGPR cliff: occ 20%->11%).
__global__ __launch_bounds__(256, 4) void k_heads(const float* __restrict__ x,
        const float* __restrict__ Wf, const float* __restrict__ st,
        const float* __restrict__ fb1, const float* __restrict__ fw2, const float* __restrict__ fb2,
        const float* __restrict__ qb1, const float* __restrict__ qw2, const float* __restrict__ qb2,
        float* __restrict__ J, float* __restrict__ outp){
    int wv = threadIdx.x >> 6, lane = threadIdx.x & 63;
    int l15 = lane & 15, lg = lane >> 4;
    int px0 = blockIdx.x*256 + wv*64;
    int b = px0 >> 16;
    int hwbase = px0 & (HW-1);
    const float* xb = x + (size_t)b*64*HW;
    const bf16x8* WfH = (const bf16x8*)Wf;

    // A fragments: 4 M-tiles x 2 k-steps, hi/lo bf16 via cvt_pk
    bf16x8 Ahi[4][2], Alo[4][2];
    #pragma unroll
    for (int mt=0; mt<4; ++mt){
        int px = hwbase + mt*16 + l15;
        #pragma unroll
        for (int ks=0; ks<2; ++ks){
            float f[8];
            #pragma unroll
            for (int j=0; j<8; ++j)
                f[j] = xb[(size_t)((ks*32 + lg*8 + j))*HW + px];
            split8(f, Ahi[mt][ks], Alo[mt][ks]);
        }
    }

    #pragma unroll
    for (int ph=0; ph<2; ++ph){
        const float* b1p = ph ? qb1 : fb1;
        const float* w2p = ph ? qw2 : fw2;
        const float* b2p = ph ? qb2 : fb2;

        float p0[16], p1[16];
        #pragma unroll
        for (int t=0;t<16;++t){ p0[t]=0.f; p1[t]=0.f; }

        for (int n=0; n<4; ++n){
            int oc = n*16 + l15;
            bf16x8 Bhi[2], Blo[2];
            #pragma unroll
            for (int ks=0; ks<2; ++ks){
                int idx = ((ph*4+n)*2+ks)*64 + lane;
                Bhi[ks] = WfH[idx];
                Blo[ks] = WfH[1024 + idx];
            }
            float bias = b1p[oc];
            float w2a = w2p[oc], w2b = w2p[64+oc];
            #pragma unroll
            for (int mt=0; mt<4; ++mt){
                f32x4 d = {0.f,0.f,0.f,0.f};
                #pragma unroll
                for (int ks=0; ks<2; ++ks){
                    d = __builtin_amdgcn_mfma_f32_16x16x32_bf16(Ahi[mt][ks], Bhi[ks], d, 0,0,0);
                    d = __builtin_amdgcn_mfma_f32_16x16x32_bf16(Ahi[mt][ks], Blo[ks], d, 0,0,0);
                    d = __builtin_amdgcn_mfma_f32_16x16x32_bf16(Alo[mt][ks], Bhi[ks], d, 0,0,0);
                }
                #pragma unroll
                for (int r=0;r<4;++r){
                    float g = gelu_f(d[r] + bias);
                    p0[mt*4+r] = fmaf(w2a, g, p0[mt*4+r]);
                    p1[mt*4+r] = fmaf(w2b, g, p1[mt*4+r]);
                }
            }
        }
        #pragma unroll
        for (int t=0;t<16;++t){
            #pragma unroll
            for (int off=1; off<16; off<<=1){
                p0[t] += __shfl_xor(p0[t], off, 64);
                p1[t] += __shfl_xor(p1[t], off, 64);
            }
        }
        float bo0 = b2p[0], bo1 = b2p[1];
        if (ph == 0){
            // flux head -> J (consumed by spectral divergence)
            if (l15 == 0){
                float* plane = J + ((size_t)(b*2 + 0))*HW;
                #pragma unroll
                for (int mt=0; mt<4; ++mt){
                    int px = hwbase + mt*16 + lg*4;
                    float4 v; v.x=p0[mt*4+0]+bo0; v.y=p0[mt*4+1]+bo0; v.z=p0[mt*4+2]+bo0; v.w=p0[mt*4+3]+bo0;
                    *(float4*)(plane + px) = v;
                }
            } else if (l15 == 1){
                float* plane = J + ((size_t)(b*2 + 1))*HW;
                #pragma unroll
                for (int mt=0; mt<4; ++mt){
                    int px = hwbase + mt*16 + lg*4;
                    float4 v; v.x=p1[mt*4+0]+bo1; v.y=p1[mt*4+1]+bo1; v.z=p1[mt*4+2]+bo1; v.w=p1[mt*4+3]+bo1;
                    *(float4*)(plane + px) = v;
                }
            }
        } else {
            // polarization head: write pred P and dt P planes directly (k_final fused)
            if (l15 < 2){
                const float* pv = (l15==0)? p0 : p1;
                float bN = (l15==0)? bo0 : bo1;
                const float* plane_st  = st   + ((size_t)(b*3+1+l15))*HW;
                float* plane_pred      = outp + ((size_t)(b*3+1+l15))*HW;
                float* plane_dt        = outp + 1572864 + ((size_t)(b*3+1+l15))*HW;
                #pragma unroll
                for (int mt=0; mt<4; ++mt){
                    int px = hwbase + mt*16 + lg*4;
                    float4 sv = *(const float4*)(plane_st + px);
                    float4 dt, pd;
                    dt.x = pv[mt*4+0]+bN; dt.y = pv[mt*4+1]+bN;
                    dt.z = pv[mt*4+2]+bN; dt.w = pv[mt*4+3]+bN;
                    pd.x = fmaf(0.05f, dt.x, sv.x); pd.y = fmaf(0.05f, dt.y, sv.y);
                    pd.z = fmaf(0.05f, dt.z, sv.z); pd.w = fmaf(0.05f, dt.w, sv.w);
                    *(float4*)(plane_pred + px) = pd;
                    *(float4*)(plane_dt + px)   = dt;
                }
            }
        }
    }
}

// F1[b,f,h,kx] = (1/16) sum_w J[row,w] e^{-i th kx w} — 4 interleaved phasor chains
__global__ __launch_bounds__(192) void k_rfftW(const float* __restrict__ J, float* __restrict__ F1x, float* __restrict__ F1y){
    int row = blockIdx.x;             // (b*2+f)*256 + h
    int kx = threadIdx.x;
    if (kx < 129){
        const float* rp = J + (size_t)row*256;
        float c1, s1; sincosf((float)kx*TH_, &s1, &c1);
        float c2 = c1*c1 - s1*s1, s2 = 2.f*c1*s1;
        float c4 = c2*c2 - s2*s2, s4 = 2.f*c2*s2;
        float pr[4], pi[4];
        pr[0]=1.f;  pi[0]=0.f;
        pr[1]=c1;   pi[1]=-s1;
        pr[2]=c2;   pi[2]=-s2;
        pr[3]=c2*c1 - s2*s1; pi[3]=-(c2*s1 + s2*c1);
        float ar[4]={0.f,0.f,0.f,0.f}, ai[4]={0.f,0.f,0.f,0.f};
        for (int w4=0; w4<64; ++w4){
            #pragma unroll
            for (int r=0;r<4;++r){
                float v = rp[w4*4+r];
                ar[r] = fmaf(v, pr[r], ar[r]);
                ai[r] = fmaf(v, pi[r], ai[r]);
                float nr = pr[r]*c4 + pi[r]*s4;   // * e^{-i 4 th kx}
                pi[r] = pi[r]*c4 - pr[r]*s4;
                pr[r] = nr;
            }
        }
        float arr = (ar[0]+ar[1])+(ar[2]+ar[3]);
        float aii = (ai[0]+ai[1])+(ai[2]+ai[3]);
        int f = (row >> 8) & 1;
        int bh = ((row >> 9) << 8) | (row & 255);
        float2* op = (float2*)(f ? F1y : F1x) + (size_t)bh*129 + kx;
        *op = make_float2(arr*(1.f/16.f), aii*(1.f/16.f));
    }
}

// F2[b,ky,kx] = (1/16)( i*fy(ky)*fftH(F1x) + i*fx(kx)*fftH(F1y) ) — 4 chains
__global__ __launch_bounds__(256) void k_fftHdiv(const float* __restrict__ F1x, const float* __restrict__ F1y, float* __restrict__ F2){
    int b = blockIdx.x / 129, kx = blockIdx.x % 129;
    int ky = threadIdx.x;
    const float2* px = (const float2*)F1x + (size_t)b*256*129 + kx;
    const float2* py = (const float2*)F1y + (size_t)b*256*129 + kx;
    float c1, s1; sincosf((float)ky*TH_, &s1, &c1);
    float c2 = c1*c1 - s1*s1, s2 = 2.f*c1*s1;
    float c4 = c2*c2 - s2*s2, s4 = 2.f*c2*s2;
    float pr[4], pi[4];
    pr[0]=1.f;  pi[0]=0.f;
    pr[1]=c1;   pi[1]=-s1;
    pr[2]=c2;   pi[2]=-s2;
    pr[3]=c2*c1 - s2*s1; pi[3]=-(c2*s1 + s2*c1);
    float xr[4]={0,0,0,0}, xi[4]={0,0,0,0}, yr[4]={0,0,0,0}, yi[4]={0,0,0,0};
    for (int h4=0; h4<64; ++h4){
        #pragma unroll
        for (int r=0;r<4;++r){
            float2 vx = px[(size_t)(h4*4+r)*129];
            float2 vy = py[(size_t)(h4*4+r)*129];
            xr[r] += vx.x*pr[r] - vx.y*pi[r];  xi[r] += vx.x*pi[r] + vx.y*pr[r];
            yr[r] += vy.x*pr[r] - vy.y*pi[r];  yi[r] += vy.x*pi[r] + vy.y*pr[r];
            float nr = pr[r]*c4 + pi[r]*s4;   // * e^{-i 4 th ky}
            pi[r] = pi[r]*c4 - pr[r]*s4;
            pr[r] = nr;
        }
    }
    float xrt = (xr[0]+xr[1])+(xr[2]+xr[3]);
    float xit = (xi[0]+xi[1])+(xi[2]+xi[3]);
    float yrt = (yr[0]+yr[1])+(yr[2]+yr[3]);
    float yit = (yi[0]+yi[1])+(yi[2]+yi[3]);
    float fy = (ky < 128)? (float)ky : (float)(ky-256);
    float fx = (kx < 128)? (float)kx : -128.f;
    float dr = -(fy*xit + fx*yit) * (1.f/16.f);
    float di =  (fy*xrt + fx*yrt) * (1.f/16.f);
    ((float2*)F2)[(size_t)(b*256+ky)*129 + kx] = make_float2(dr, di);
}

// F3[b,h,kx] = (1/16) sum_ky F2 e^{+i th ky h} — 4 chains
__global__ __launch_bounds__(256) void k_ifftH(const float* __restrict__ F2, float* __restrict__ F3){
    int b = blockIdx.x / 129, kx = blockIdx.x % 129;
    int h = threadIdx.x;
    const float2* p2 = (const float2*)F2 + (size_t)b*256*129 + kx;
    float c1, s1; sincosf((float)h*TH_, &s1, &c1);
    float c2 = c1*c1 - s1*s1, s2 = 2.f*c1*s1;
    float c4 = c2*c2 - s2*s2, s4 = 2.f*c2*s2;
    float pr[4], pi[4];
    pr[0]=1.f;  pi[0]=0.f;
    pr[1]=c1;   pi[1]=s1;
    pr[2]=c2;   pi[2]=s2;
    pr[3]=c2*c1 - s2*s1; pi[3]=c2*s1 + s2*c1;
    float ar[4]={0,0,0,0}, ai[4]={0,0,0,0};
    for (int k4=0; k4<64; ++k4){
        #pragma unroll
        for (int r=0;r<4;++r){
            float2 v = p2[(size_t)(k4*4+r)*129];
            ar[r] += v.x*pr[r] - v.y*pi[r];
            ai[r] += v.x*pi[r] + v.y*pr[r];
            float nr = pr[r]*c4 - pi[r]*s4;   // * e^{+i 4 th h}
            pi[r] = pi[r]*c4 + pr[r]*s4;
            pr[r] = nr;
        }
    }
    float arr = (ar[0]+ar[1])+(ar[2]+ar[3]);
    float aii = (ai[0]+ai[1])+(ai[2]+ai[3]);
    ((float2*)F3)[(size_t)(b*256+h)*129 + kx] = make_float2(arr*(1.f/16.f), aii*(1.f/16.f));
}

// dt_rho = -irfftW(F3); pred rho (softplus10) + dt rho — 4 chains over kx=1..128
__global__ __launch_bounds__(256) void k_irfftW(const float* __restrict__ F3, const float* __restrict__ st, float* __restrict__ outp){
    int b = blockIdx.x >> 8, h = blockIdx.x & 255;
    int w = threadIdx.x;
    const float2* rp = (const float2*)F3 + (size_t)(b*256+h)*129;
    float c1, s1; sincosf((float)w*TH_, &s1, &c1);
    float c2 = c1*c1 - s1*s1, s2 = 2.f*c1*s1;
    float c3 = c2*c1 - s2*s1, s3 = c2*s1 + s2*c1;
    float c4 = c2*c2 - s2*s2, s4 = 2.f*c2*s2;
    float pr[4] = {c1, c2, c3, c4};
    float pi[4] = {s1, s2, s3, s4};        // e^{+i th w kx}, kx=1..4
    float acc[4] = {0.f,0.f,0.f,0.f};
    for (int t=0; t<32; ++t){
        #pragma unroll
        for (int r=0;r<4;++r){
            float2 v = rp[1 + t*4 + r];
            acc[r] += v.x*pr[r] - v.y*pi[r];
            float nr = pr[r]*c4 - pi[r]*s4;   // * e^{+i 4 th w}
            pi[r] = pi[r]*c4 + pr[r]*s4;
            pr[r] = nr;
        }
    }
    float2 b0 = rp[0];
    float2 v128 = rp[128];
    float nyq = (w & 1)? -v128.x : v128.x;
    // chains covered kx=1..128 with weight 2; Nyquist belongs with weight 1 -> subtract once
    float y = b0.x + 2.f*((acc[0]+acc[1])+(acc[2]+acc[3])) - nyq;
    y *= (1.f/16.f);
    float rho = -y;
    int hw = h*256 + w;
    float s0 = st[(size_t)(b*3)*HW + hw];
    float t = 10.f*fmaf(0.05f, rho, s0);
    float sp = fmaxf(t, 0.f) + log1pf(expf(-fabsf(t)));
    outp[(size_t)(b*3)*HW + hw] = 0.1f*sp;
    outp[(size_t)1572864 + (size_t)(b*3)*HW + hw] = rho;
}

extern "C" void kernel_launch(void* const* d_in, const int* in_sizes, int n_in,
                              void* d_out, int out_size, void* d_ws, size_t ws_size,
                              hipStream_t stream){
    const float* state = (const float*)d_in[0];
    const float* lw  = (const float*)d_in[1];
    const float* lb  = (const float*)d_in[2];
    const float* swr = (const float*)d_in[3];
    const float* swi = (const float*)d_in[4];
    const float* pww = (const float*)d_in[5];
    // d_in[6] = pw_b : cancels exactly in InstanceNorm, unused
    const float* fw1 = (const float*)d_in[7];
    const float* fb1 = (const float*)d_in[8];
    const float* fw2 = (const float*)d_in[9];
    const float* fb2 = (const float*)d_in[10];
    const float* qw1 = (const float*)d_in[11];
    const float* qb1 = (const float*)d_in[12];
    const float* qw2 = (const float*)d_in[13];
    const float* qb2 = (const float*)d_in[14];
    float* outp = (float*)d_out;
    float* ws = (float*)d_ws;

    float* x   = ws;                    // 33,554,432 f32
    float* S   = x   + 33554432;        // 16,384
    float* A   = S   + 16384;           // 262,144
    float* CS  = A   + 262144;          // 262,144
    float* J   = CS  + 262144;          // 1,048,576
    float* F1x = J   + 1048576;         // 528,384
    float* F1y = F1x + 528384;          // 528,384
    float* F2  = F1y + 528384;          // 528,384
    float* F3  = F2  + 528384;          // 528,384
    float* GH  = F3  + 528384;          // 512
    float* Wf  = GH  + 512;             // 32,768 B worth of frags (8,192 f32 slots)
    float* T   = J;                     // alias: T dead before k_heads writes J

    hipLaunchKernelGGL(k_tables, dim3(1), dim3(256), 0, stream, GH);
    hipLaunchKernelGGL(k_prepW,  dim3(4), dim3(256), 0, stream, fw1, qw1, Wf);
    hipLaunchKernelGGL(k_lift, dim3(2048), dim3(256), 0, stream, state, lw, lb, x);
    for (int l=0; l<4; ++l){
        if (l == 0)
            hipLaunchKernelGGL(k_analysis, dim3(512), dim3(256), 0, stream, x, GH, S);
        else
            hipLaunchKernelGGL(k_analysisT, dim3(512), dim3(256), 0, stream, T, S);
        hipLaunchKernelGGL(k_mixA, dim3(512), dim3(256), 0, stream, S,
                           swr + (size_t)l*1048576, swi + (size_t)l*1048576, A);
        hipLaunchKernelGGL(k_mixB, dim3(512), dim3(256), 0, stream, A, pww + l*4096, CS);
        if (l < 3)
            hipLaunchKernelGGL((k_synth<true>),  dim3(2048), dim3(256), 0, stream, CS, x, GH, T);
        else
            hipLaunchKernelGGL((k_synth<false>), dim3(2048), dim3(256), 0, stream, CS, x, GH, T);
    }
    hipLaunchKernelGGL(k_heads, dim3(2048), dim3(256), 0, stream, x,
                       Wf, state, fb1, fw2, fb2, qb1, qw2, qb2, J, outp);
    hipLaunchKernelGGL(k_rfftW,  dim3(4096), dim3(192), 0, stream, J, F1x, F1y);
    hipLaunchKernelGGL(k_fftHdiv, dim3(1032), dim3(256), 0, stream, F1x, F1y, F2);
    hipLaunchKernelGGL(k_ifftH,  dim3(1032), dim3(256), 0, stream, F2, F3);
    hipLaunchKernelGGL(k_irfftW, dim3(2048), dim3(256), 0, stream, F3, state, outp);
}

// Round 7
// 624.969 us; speedup vs baseline: 1.1515x; 1.1515x over previous
//
#include <hip/hip_runtime.h>
#include <math.h>

#define HW 65536
#define TH_ 0.024543692606170259f  // 2*pi/256

typedef __attribute__((ext_vector_type(8))) short bf16x8;
typedef __attribute__((ext_vector_type(4))) float f32x4;

// Fast gelu: Abramowitz-Stegun 7.1.26 erf, |abs err| ~3e-7.
__device__ __forceinline__ float gelu_f(float v){
    float u = fabsf(v)*0.7071067811865476f;
    float t = __builtin_amdgcn_rcpf(fmaf(0.3275911f, u, 1.0f));
    float p = t*fmaf(t, fmaf(t, fmaf(t, fmaf(t, 1.061405429f, -1.453152027f),
                     1.421413741f), -0.284496736f), 0.254829592f);
    float e = __expf(-u*u);
    float erfu = fmaf(-p, e, 1.0f);
    float er = copysignf(erfu, v);
    return 0.5f*v*(1.0f+er);
}

__device__ __forceinline__ short f2bf(float f){
    union { float f; unsigned u; } v; v.f = f;
    unsigned r = (v.u + 0x7FFF + ((v.u >> 16) & 1)) >> 16;   // RNE
    return (short)r;
}
__device__ __forceinline__ float bf2f(short s){
    union { float f; unsigned u; } v; v.u = ((unsigned)(unsigned short)s) << 16;
    return v.f;
}

// v_cvt_pk_bf16_f32: D.lo = bf16(S0), D.hi = bf16(S1)
__device__ __forceinline__ unsigned cvt_pk_bf16(float lo, float hi){
    unsigned r;
    asm("v_cvt_pk_bf16_f32 %0, %1, %2" : "=v"(r) : "v"(lo), "v"(hi));
    return r;
}

union U8 { bf16x8 v; unsigned u[4]; };

// split 8 floats -> hi/lo bf16x8 using packed converts
__device__ __forceinline__ void split8(const float* f, bf16x8& H, bf16x8& L){
    U8 h, l;
    #pragma unroll
    for (int p=0;p<4;++p){
        float a = f[2*p], b = f[2*p+1];
        unsigned hp = cvt_pk_bf16(a, b);
        union { unsigned u; float fl; } ua, ub;
        ua.u = hp << 16; ub.u = hp & 0xffff0000u;
        h.u[p] = hp;
        l.u[p] = cvt_pk_bf16(a - ua.fl, b - ub.fl);
    }
    H = h.v; L = l.v;
}

// GH[h] = sum_{ky<16} e^{-2pi i ky h /256}
__global__ void k_tables(float* __restrict__ GH){
    int h = threadIdx.x;
    double gr = 0.0, gi = 0.0;
    for (int ky=0; ky<16; ++ky){
        double a = -2.0*3.14159265358979323846*(double)(ky*h)/256.0;
        gr += cos(a); gi += sin(a);
    }
    GH[2*h] = (float)gr; GH[2*h+1] = (float)gi;
}

// Precompute split-bf16 W1 fragments for k_heads.
__global__ __launch_bounds__(256) void k_prepW(const float* __restrict__ fw1, const float* __restrict__ qw1,
                                               float* __restrict__ Wf){
    int t = blockIdx.x*256 + threadIdx.x;       // 1024 total
    int lane = t & 63, ks = (t>>6)&1, n = (t>>7)&3, ph = (t>>9)&1;
    int l15 = lane & 15, lg = lane >> 4;
    const float* w1p = ph ? qw1 : fw1;
    int oc = n*16 + l15;
    U8 h, l;
    #pragma unroll
    for (int p=0;p<4;++p){
        float a = w1p[oc*64 + ks*32 + lg*8 + 2*p];
        float b = w1p[oc*64 + ks*32 + lg*8 + 2*p+1];
        short ha = f2bf(a), hb = f2bf(b);
        h.u[p] = ((unsigned)(unsigned short)ha) | (((unsigned)(unsigned short)hb)<<16);
        short la = f2bf(a - bf2f(ha)), lb = f2bf(b - bf2f(hb));
        l.u[p] = ((unsigned)(unsigned short)la) | (((unsigned)(unsigned short)lb)<<16);
    }
    int idx = ((ph*4+n)*2+ks)*64 + lane;
    ((bf16x8*)Wf)[idx] = h.v;
    ((bf16x8*)Wf)[1024 + idx] = l.v;
}

// x[b,c,hw] = gelu(sum_i lw[c,i]*state[b,i,hw] + lb[c])
__global__ __launch_bounds__(256) void k_lift(const float* __restrict__ st, const float* __restrict__ lw,
                                              const float* __restrict__ lb, float* __restrict__ x){
    int p = blockIdx.x*256 + threadIdx.x;
    int b = p >> 16, hw = p & (HW-1);
    float s0 = st[(b*3+0)*HW + hw];
    float s1 = st[(b*3+1)*HW + hw];
    float s2 = st[(b*3+2)*HW + hw];
    float* xp = x + (size_t)b*64*HW + hw;
    for (int c=0;c<64;++c){
        float v = fmaf(lw[c*3], s0, fmaf(lw[c*3+1], s1, fmaf(lw[c*3+2], s2, lb[c])));
        xp[(size_t)c*HW] = gelu_f(v);
    }
}

// Layer-0 analysis (reads x)
__global__ __launch_bounds__(256) void k_analysis(const float* __restrict__ x, const float* __restrict__ GH,
                                                  float* __restrict__ S){
    int b = blockIdx.x >> 6, i = blockIdx.x & 63;
    int w = threadIdx.x;
    const float* xp = x + ((size_t)(b*64+i))*HW + w;
    float Tr = 0.f, Ti = 0.f;
    #pragma unroll 4
    for (int h=0; h<256; ++h){
        float v = xp[h*256];
        Tr = fmaf(GH[2*h],   v, Tr);
        Ti = fmaf(GH[2*h+1], v, Ti);
    }
    float c1, s1; sincosf((float)w * TH_, &s1, &c1);
    float Sr[16], Si[16];
    float ck = 1.f, sk = 0.f;
    #pragma unroll
    for (int k=0;k<16;++k){
        Sr[k] = Tr*ck + Ti*sk;     // T * e^{-i th k w}
        Si[k] = Ti*ck - Tr*sk;
        float nc = ck*c1 - sk*s1;
        sk = ck*s1 + sk*c1;
        ck = nc;
    }
    #pragma unroll
    for (int k=0;k<16;++k){
        #pragma unroll
        for (int off=32; off; off>>=1){
            Sr[k] += __shfl_xor(Sr[k], off, 64);
            Si[k] += __shfl_xor(Si[k], off, 64);
        }
    }
    __shared__ float red[4][32];
    int wv = threadIdx.x >> 6, ln = threadIdx.x & 63;
    if (ln == 0){
        #pragma unroll
        for (int k=0;k<16;++k){ red[wv][2*k] = Sr[k]; red[wv][2*k+1] = Si[k]; }
    }
    __syncthreads();
    if (threadIdx.x < 32){
        float v = red[0][threadIdx.x]+red[1][threadIdx.x]+red[2][threadIdx.x]+red[3][threadIdx.x];
        S[(b*64+i)*32 + threadIdx.x] = v * (1.0f/256.0f);
    }
}

// Layers 1-3: analysis from fused T[b,i,w]
__global__ __launch_bounds__(256) void k_analysisT(const float* __restrict__ T, float* __restrict__ S){
    int bi = blockIdx.x;               // b*64+i
    int w = threadIdx.x;
    float2 t = ((const float2*)T)[bi*256 + w];
    float Tr = t.x, Ti = t.y;
    float c1, s1; sincosf((float)w * TH_, &s1, &c1);
    float Sr[16], Si[16];
    float ck = 1.f, sk = 0.f;
    #pragma unroll
    for (int k=0;k<16;++k){
        Sr[k] = Tr*ck + Ti*sk;
        Si[k] = Ti*ck - Tr*sk;
        float nc = ck*c1 - sk*s1;
        sk = ck*s1 + sk*c1;
        ck = nc;
    }
    #pragma unroll
    for (int k=0;k<16;++k){
        #pragma unroll
        for (int off=32; off; off>>=1){
            Sr[k] += __shfl_xor(Sr[k], off, 64);
            Si[k] += __shfl_xor(Si[k], off, 64);
        }
    }
    __shared__ float red[4][32];
    int wv = threadIdx.x >> 6, ln = threadIdx.x & 63;
    if (ln == 0){
        #pragma unroll
        for (int k=0;k<16;++k){ red[wv][2*k] = Sr[k]; red[wv][2*k+1] = Si[k]; }
    }
    __syncthreads();
    if (threadIdx.x < 32){
        float v = red[0][threadIdx.x]+red[1][threadIdx.x]+red[2][threadIdx.x]+red[3][threadIdx.x];
        S[bi*32 + threadIdx.x] = v * (1.0f/256.0f);
    }
}

// A[b,j,km] = sum_i S[b,i,k] * (wr + i wi)[i,j,km]
__global__ __launch_bounds__(256) void k_mixA(const float* __restrict__ S, const float* __restrict__ wr,
                                              const float* __restrict__ wi, float* __restrict__ A){
    int j = blockIdx.x >> 3, b = blockIdx.x & 7;
    __shared__ float sS[2048];
    for (int t=threadIdx.x; t<2048; t+=256) sS[t] = S[b*2048 + t];
    __syncthreads();
    int km = threadIdx.x, k = km >> 4;
    float ar = 0.f, ai = 0.f;
    const float* wrp = wr + j*256 + km;
    const float* wip = wi + j*256 + km;
    #pragma unroll 4
    for (int i=0;i<64;++i){
        float wrv = wrp[i*16384];
        float wiv = wip[i*16384];
        float2 sv = ((const float2*)sS)[i*16 + k];
        ar += sv.x*wrv - sv.y*wiv;
        ai += sv.x*wiv + sv.y*wrv;
    }
    ((float2*)A)[(b*64 + j)*256 + km] = make_float2(ar, ai);
}

// c = sum_j pw[o,j]*A[b,j,km]; Parseval stats; CS = c * inv_sigma * alpha(m) / 256
__global__ __launch_bounds__(256) void k_mixB(const float* __restrict__ A, const float* __restrict__ pw,
                                              float* __restrict__ CS){
    int b = blockIdx.x >> 6, o = blockIdx.x & 63;
    int km = threadIdx.x, m = km & 15;
    const float2* Ap = (const float2*)A + b*64*256 + km;
    const float* pwp = pw + o*64;
    float cr=0.f, ci=0.f;
    #pragma unroll 4
    for (int j=0;j<64;++j){
        float p = pwp[j];
        float2 a = Ap[j*256];
        cr = fmaf(p, a.x, cr);
        ci = fmaf(p, a.y, ci);
    }
    float aw = (m==0)? 1.f : 4.f;          // alpha(m)^2
    float s = (km==0)? 0.f : aw*(cr*cr + ci*ci);
    #pragma unroll
    for (int off=32; off; off>>=1) s += __shfl_xor(s, off, 64);
    __shared__ float rsum[4];
    __shared__ float sinv;
    if ((threadIdx.x & 63) == 0) rsum[threadIdx.x>>6] = s;
    __syncthreads();
    if (threadIdx.x == 0){
        float var = (rsum[0]+rsum[1]+rsum[2]+rsum[3]) * (1.0f/131072.0f); // /(2*H*W)
        sinv = rsqrtf(var + 1e-5f);
    }
    __syncthreads();
    float alpha = (m==0)? 1.f : 2.f;
    float sc = sinv * alpha * (1.0f/256.0f);
    if (km == 0) cr = 0.f;                 // remove mean (DC real part)
    ((float2*)CS)[blockIdx.x*256 + km] = make_float2(cr*sc, ci*sc);
}

// x += gelu(irfft-ish synth); LDS-shared V; optional T-emit.
template<bool EMIT_T>
__global__ __launch_bounds__(256) void k_synth(const float* __restrict__ CS, float* __restrict__ x,
                                               const float* __restrict__ GH, float* __restrict__ T){
    int bo = blockIdx.x >> 2, wt = blockIdx.x & 3;
    int lane = threadIdx.x & 63, wv = threadIdx.x >> 6;
    int w = wt*64 + lane;
    __shared__ float sGH[512];
    __shared__ float2 sV[16][64];
    if (EMIT_T){
        sGH[threadIdx.x] = GH[threadIdx.x];
        sGH[256+threadIdx.x] = GH[256+threadIdx.x];
    }
    const float2* cs = (const float2*)CS + bo*256;
    {   // phase A: thread computes V[k] for k in [4*wv, 4*wv+4)
        float Vr[4] = {0.f,0.f,0.f,0.f}, Vi[4] = {0.f,0.f,0.f,0.f};
        float stepc, steps; sincosf((float)w*TH_, &steps, &stepc);
        float pc = 1.f, ps = 0.f;          // e^{+i m th w}
        for (int m=0;m<16;++m){
            #pragma unroll
            for (int kk=0;kk<4;++kk){
                float2 a = cs[(wv*4+kk)*16 + m];
                Vr[kk] += a.x*pc - a.y*ps;
                Vi[kk] += a.x*ps + a.y*pc;
            }
            float nc = pc*stepc - ps*steps;
            ps = pc*steps + ps*stepc;
            pc = nc;
        }
        #pragma unroll
        for (int kk=0;kk<4;++kk) sV[wv*4+kk][lane] = make_float2(Vr[kk], Vi[kk]);
    }
    __syncthreads();
    int h0 = wv*16;
    float rc[16], rs[16], qr[16], qi[16];
    #pragma unroll
    for (int k=0;k<16;++k){
        float2 v = sV[k][lane];
        sincosf((float)k*TH_, &rs[k], &rc[k]);
        float c0, s0; sincosf((float)(k*h0)*TH_, &s0, &c0);
        qr[k] = v.x*c0 - v.y*s0;       // q = V * e^{+i th k h0}
        qi[k] = v.x*s0 + v.y*c0;
    }
    float* xp = x + ((size_t)bo << 16);
    float Tr = 0.f, Ti = 0.f;
    for (int i=0;i<16;++i){
        float y0=0.f,y1=0.f,y2=0.f,y3=0.f;
        #pragma unroll
        for (int k=0;k<16;++k){
            float re = qr[k], im = qi[k];
            y0 += re;                                   // h
            if ((k&3)==0)      { y1 += re; y2 += re; y3 += re; }   // *i^k, *(-1)^k, *(-i)^k
            else if ((k&3)==1) { y1 -= im; y2 -= re; y3 += im; }
            else if ((k&3)==2) { y1 -= re; y2 += re; y3 -= re; }
            else               { y1 += im; y2 -= re; y3 -= im; }
        }
        #pragma unroll
        for (int k=1;k<16;++k){
            float nr = qr[k]*rc[k] - qi[k]*rs[k];
            qi[k]    = qr[k]*rs[k] + qi[k]*rc[k];
            qr[k] = nr;
        }
        int p0 = (h0+i)*256 + w;
        float x0 = xp[p0], x1 = xp[p0+16384], x2 = xp[p0+32768], x3 = xp[p0+49152];
        float n0 = gelu_f(y0) + x0;
        float n1 = gelu_f(y1) + x1;
        float n2 = gelu_f(y2) + x2;
        float n3 = gelu_f(y3) + x3;
        xp[p0]       = n0;
        xp[p0+16384] = n1;
        xp[p0+32768] = n2;
        xp[p0+49152] = n3;
        if (EMIT_T){
            int h = h0+i;
            Tr = fmaf(sGH[2*h],     n0, Tr);  Ti = fmaf(sGH[2*h+1],     n0, Ti);
            Tr = fmaf(sGH[2*h+128], n1, Tr);  Ti = fmaf(sGH[2*h+129],   n1, Ti);
            Tr = fmaf(sGH[2*h+256], n2, Tr);  Ti = fmaf(sGH[2*h+257],   n2, Ti);
            Tr = fmaf(sGH[2*h+384], n3, Tr);  Ti = fmaf(sGH[2*h+385],   n3, Ti);
        }
    }
    if (EMIT_T){
        __shared__ float2 tpart[4][64];
        tpart[wv][lane] = make_float2(Tr, Ti);
        __syncthreads();
        if (wv == 0){
            float2 a = tpart[0][lane], b2 = tpart[1][lane];
            float2 c = tpart[2][lane], d = tpart[3][lane];
            ((float2*)T)[bo*256 + w] = make_float2(a.x+b2.x+c.x+d.x, a.y+b2.y+c.y+d.y);
        }
    }
}

// MFMA heads; Wf staged via LDS (keeps VGPR<=128: R5's global-load Wf hit 132 VGPR
// -> occupancy halved; R6's launch_bounds(256,4) forced VGPR=64 -> 250MB spills).
// ph=1 (polarization) writes final outputs directly (k_final fused).
__global__ __launch_bounds__(256) void k_heads(const float* __restrict__ x,
        const float* __restrict__ Wf, const float* __restrict__ st,
        const float* __restrict__ fb1, const float* __restrict__ fw2, const float* __restrict__ fb2,
        const float* __restrict__ qb1, const float* __restrict__ qw2, const float* __restrict__ qb2,
        float* __restrict__ J, float* __restrict__ outp){
    __shared__ bf16x8 sWf[2048];       // 32 KB: full split-bf16 W1 fragment table
    for (int t = threadIdx.x; t < 2048; t += 256)
        sWf[t] = ((const bf16x8*)Wf)[t];
    __syncthreads();

    int wv = threadIdx.x >> 6, lane = threadIdx.x & 63;
    int l15 = lane & 15, lg = lane >> 4;
    int px0 = blockIdx.x*256 + wv*64;
    int b = px0 >> 16;
    int hwbase = px0 & (HW-1);
    const float* xb = x + (size_t)b*64*HW;

    // A fragments: 4 M-tiles x 2 k-steps, hi/lo bf16 via cvt_pk
    bf16x8 Ahi[4][2], Alo[4][2];
    #pragma unroll
    for (int mt=0; mt<4; ++mt){
        int px = hwbase + mt*16 + l15;
        #pragma unroll
        for (int ks=0; ks<2; ++ks){
            float f[8];
            #pragma unroll
            for (int j=0; j<8; ++j)
                f[j] = xb[(size_t)((ks*32 + lg*8 + j))*HW + px];
            split8(f, Ahi[mt][ks], Alo[mt][ks]);
        }
    }

    #pragma unroll
    for (int ph=0; ph<2; ++ph){
        const float* b1p = ph ? qb1 : fb1;
        const float* w2p = ph ? qw2 : fw2;
        const float* b2p = ph ? qb2 : fb2;

        float p0[16], p1[16];
        #pragma unroll
        for (int t=0;t<16;++t){ p0[t]=0.f; p1[t]=0.f; }

        for (int n=0; n<4; ++n){
            int oc = n*16 + l15;
            float bias = b1p[oc];
            float w2a = w2p[oc], w2b = w2p[64+oc];
            int base = ((ph*4+n)*2)*64 + lane;
            bf16x8 Bhi0 = sWf[base];
            bf16x8 Bhi1 = sWf[base + 64];
            bf16x8 Blo0 = sWf[1024 + base];
            bf16x8 Blo1 = sWf[1024 + base + 64];
            #pragma unroll
            for (int mt=0; mt<4; ++mt){
                f32x4 d = {0.f,0.f,0.f,0.f};
                d = __builtin_amdgcn_mfma_f32_16x16x32_bf16(Ahi[mt][0], Bhi0, d, 0,0,0);
                d = __builtin_amdgcn_mfma_f32_16x16x32_bf16(Ahi[mt][0], Blo0, d, 0,0,0);
                d = __builtin_amdgcn_mfma_f32_16x16x32_bf16(Alo[mt][0], Bhi0, d, 0,0,0);
                d = __builtin_amdgcn_mfma_f32_16x16x32_bf16(Ahi[mt][1], Bhi1, d, 0,0,0);
                d = __builtin_amdgcn_mfma_f32_16x16x32_bf16(Ahi[mt][1], Blo1, d, 0,0,0);
                d = __builtin_amdgcn_mfma_f32_16x16x32_bf16(Alo[mt][1], Bhi1, d, 0,0,0);
                #pragma unroll
                for (int r=0;r<4;++r){
                    float g = gelu_f(d[r] + bias);
                    p0[mt*4+r] = fmaf(w2a, g, p0[mt*4+r]);
                    p1[mt*4+r] = fmaf(w2b, g, p1[mt*4+r]);
                }
            }
        }
        #pragma unroll
        for (int t=0;t<16;++t){
            #pragma unroll
            for (int off=1; off<16; off<<=1){
                p0[t] += __shfl_xor(p0[t], off, 64);
                p1[t] += __shfl_xor(p1[t], off, 64);
            }
        }
        float bo0 = b2p[0], bo1 = b2p[1];
        if (ph == 0){
            // flux head -> J (consumed by spectral divergence)
            if (l15 == 0){
                float* plane = J + ((size_t)(b*2 + 0))*HW;
                #pragma unroll
                for (int mt=0; mt<4; ++mt){
                    int px = hwbase + mt*16 + lg*4;
                    float4 v; v.x=p0[mt*4+0]+bo0; v.y=p0[mt*4+1]+bo0; v.z=p0[mt*4+2]+bo0; v.w=p0[mt*4+3]+bo0;
                    *(float4*)(plane + px) = v;
                }
            } else if (l15 == 1){
                float* plane = J + ((size_t)(b*2 + 1))*HW;
                #pragma unroll
                for (int mt=0; mt<4; ++mt){
                    int px = hwbase + mt*16 + lg*4;
                    float4 v; v.x=p1[mt*4+0]+bo1; v.y=p1[mt*4+1]+bo1; v.z=p1[mt*4+2]+bo1; v.w=p1[mt*4+3]+bo1;
                    *(float4*)(plane + px) = v;
                }
            }
        } else {
            // polarization head: write pred P and dt P planes directly (k_final fused)
            if (l15 < 2){
                const float* pv = (l15==0)? p0 : p1;
                float bN = (l15==0)? bo0 : bo1;
                const float* plane_st  = st   + ((size_t)(b*3+1+l15))*HW;
                float* plane_pred      = outp + ((size_t)(b*3+1+l15))*HW;
                float* plane_dt        = outp + 1572864 + ((size_t)(b*3+1+l15))*HW;
                #pragma unroll
                for (int mt=0; mt<4; ++mt){
                    int px = hwbase + mt*16 + lg*4;
                    float4 sv = *(const float4*)(plane_st + px);
                    float4 dt, pd;
                    dt.x = pv[mt*4+0]+bN; dt.y = pv[mt*4+1]+bN;
                    dt.z = pv[mt*4+2]+bN; dt.w = pv[mt*4+3]+bN;
                    pd.x = fmaf(0.05f, dt.x, sv.x); pd.y = fmaf(0.05f, dt.y, sv.y);
                    pd.z = fmaf(0.05f, dt.z, sv.z); pd.w = fmaf(0.05f, dt.w, sv.w);
                    *(float4*)(plane_pred + px) = pd;
                    *(float4*)(plane_dt + px)   = dt;
                }
            }
        }
    }
}

// F1[b,f,h,kx] = (1/16) sum_w J[row,w] e^{-i th kx w} — 4 interleaved phasor chains
__global__ __launch_bounds__(192) void k_rfftW(const float* __restrict__ J, float* __restrict__ F1x, float* __restrict__ F1y){
    int row = blockIdx.x;             // (b*2+f)*256 + h
    int kx = threadIdx.x;
    if (kx < 129){
        const float* rp = J + (size_t)row*256;
        float c1, s1; sincosf((float)kx*TH_, &s1, &c1);
        float c2 = c1*c1 - s1*s1, s2 = 2.f*c1*s1;
        float c4 = c2*c2 - s2*s2, s4 = 2.f*c2*s2;
        float pr[4], pi[4];
        pr[0]=1.f;  pi[0]=0.f;
        pr[1]=c1;   pi[1]=-s1;
        pr[2]=c2;   pi[2]=-s2;
        pr[3]=c2*c1 - s2*s1; pi[3]=-(c2*s1 + s2*c1);
        float ar[4]={0.f,0.f,0.f,0.f}, ai[4]={0.f,0.f,0.f,0.f};
        for (int w4=0; w4<64; ++w4){
            #pragma unroll
            for (int r=0;r<4;++r){
                float v = rp[w4*4+r];
                ar[r] = fmaf(v, pr[r], ar[r]);
                ai[r] = fmaf(v, pi[r], ai[r]);
                float nr = pr[r]*c4 + pi[r]*s4;   // * e^{-i 4 th kx}
                pi[r] = pi[r]*c4 - pr[r]*s4;
                pr[r] = nr;
            }
        }
        float arr = (ar[0]+ar[1])+(ar[2]+ar[3]);
        float aii = (ai[0]+ai[1])+(ai[2]+ai[3]);
        int f = (row >> 8) & 1;
        int bh = ((row >> 9) << 8) | (row & 255);
        float2* op = (float2*)(f ? F1y : F1x) + (size_t)bh*129 + kx;
        *op = make_float2(arr*(1.f/16.f), aii*(1.f/16.f));
    }
}

// F2[b,ky,kx] = (1/16)( i*fy(ky)*fftH(F1x) + i*fx(kx)*fftH(F1y) ) — 4 chains
__global__ __launch_bounds__(256) void k_fftHdiv(const float* __restrict__ F1x, const float* __restrict__ F1y, float* __restrict__ F2){
    int b = blockIdx.x / 129, kx = blockIdx.x % 129;
    int ky = threadIdx.x;
    const float2* px = (const float2*)F1x + (size_t)b*256*129 + kx;
    const float2* py = (const float2*)F1y + (size_t)b*256*129 + kx;
    float c1, s1; sincosf((float)ky*TH_, &s1, &c1);
    float c2 = c1*c1 - s1*s1, s2 = 2.f*c1*s1;
    float c4 = c2*c2 - s2*s2, s4 = 2.f*c2*s2;
    float pr[4], pi[4];
    pr[0]=1.f;  pi[0]=0.f;
    pr[1]=c1;   pi[1]=-s1;
    pr[2]=c2;   pi[2]=-s2;
    pr[3]=c2*c1 - s2*s1; pi[3]=-(c2*s1 + s2*c1);
    float xr[4]={0,0,0,0}, xi[4]={0,0,0,0}, yr[4]={0,0,0,0}, yi[4]={0,0,0,0};
    for (int h4=0; h4<64; ++h4){
        #pragma unroll
        for (int r=0;r<4;++r){
            float2 vx = px[(size_t)(h4*4+r)*129];
            float2 vy = py[(size_t)(h4*4+r)*129];
            xr[r] += vx.x*pr[r] - vx.y*pi[r];  xi[r] += vx.x*pi[r] + vx.y*pr[r];
            yr[r] += vy.x*pr[r] - vy.y*pi[r];  yi[r] += vy.x*pi[r] + vy.y*pr[r];
            float nr = pr[r]*c4 + pi[r]*s4;   // * e^{-i 4 th ky}
            pi[r] = pi[r]*c4 - pr[r]*s4;
            pr[r] = nr;
        }
    }
    float xrt = (xr[0]+xr[1])+(xr[2]+xr[3]);
    float xit = (xi[0]+xi[1])+(xi[2]+xi[3]);
    float yrt = (yr[0]+yr[1])+(yr[2]+yr[3]);
    float yit = (yi[0]+yi[1])+(yi[2]+yi[3]);
    float fy = (ky < 128)? (float)ky : (float)(ky-256);
    float fx = (kx < 128)? (float)kx : -128.f;
    float dr = -(fy*xit + fx*yit) * (1.f/16.f);
    float di =  (fy*xrt + fx*yrt) * (1.f/16.f);
    ((float2*)F2)[(size_t)(b*256+ky)*129 + kx] = make_float2(dr, di);
}

// F3[b,h,kx] = (1/16) sum_ky F2 e^{+i th ky h} — 4 chains
__global__ __launch_bounds__(256) void k_ifftH(const float* __restrict__ F2, float* __restrict__ F3){
    int b = blockIdx.x / 129, kx = blockIdx.x % 129;
    int h = threadIdx.x;
    const float2* p2 = (const float2*)F2 + (size_t)b*256*129 + kx;
    float c1, s1; sincosf((float)h*TH_, &s1, &c1);
    float c2 = c1*c1 - s1*s1, s2 = 2.f*c1*s1;
    float c4 = c2*c2 - s2*s2, s4 = 2.f*c2*s2;
    float pr[4], pi[4];
    pr[0]=1.f;  pi[0]=0.f;
    pr[1]=c1;   pi[1]=s1;
    pr[2]=c2;   pi[2]=s2;
    pr[3]=c2*c1 - s2*s1; pi[3]=c2*s1 + s2*c1;
    float ar[4]={0,0,0,0}, ai[4]={0,0,0,0};
    for (int k4=0; k4<64; ++k4){
        #pragma unroll
        for (int r=0;r<4;++r){
            float2 v = p2[(size_t)(k4*4+r)*129];
            ar[r] += v.x*pr[r] - v.y*pi[r];
            ai[r] += v.x*pi[r] + v.y*pr[r];
            float nr = pr[r]*c4 - pi[r]*s4;   // * e^{+i 4 th h}
            pi[r] = pi[r]*c4 + pr[r]*s4;
            pr[r] = nr;
        }
    }
    float arr = (ar[0]+ar[1])+(ar[2]+ar[3]);
    float aii = (ai[0]+ai[1])+(ai[2]+ai[3]);
    ((float2*)F3)[(size_t)(b*256+h)*129 + kx] = make_float2(arr*(1.f/16.f), aii*(1.f/16.f));
}

// dt_rho = -irfftW(F3); pred rho (softplus10) + dt rho — 4 chains over kx=1..128
__global__ __launch_bounds__(256) void k_irfftW(const float* __restrict__ F3, const float* __restrict__ st, float* __restrict__ outp){
    int b = blockIdx.x >> 8, h = blockIdx.x & 255;
    int w = threadIdx.x;
    const float2* rp = (const float2*)F3 + (size_t)(b*256+h)*129;
    float c1, s1; sincosf((float)w*TH_, &s1, &c1);
    float c2 = c1*c1 - s1*s1, s2 = 2.f*c1*s1;
    float c3 = c2*c1 - s2*s1, s3 = c2*s1 + s2*c1;
    float c4 = c2*c2 - s2*s2, s4 = 2.f*c2*s2;
    float pr[4] = {c1, c2, c3, c4};
    float pi[4] = {s1, s2, s3, s4};        // e^{+i th w kx}, kx=1..4
    float acc[4] = {0.f,0.f,0.f,0.f};
    for (int t=0; t<32; ++t){
        #pragma unroll
        for (int r=0;r<4;++r){
            float2 v = rp[1 + t*4 + r];
            acc[r] += v.x*pr[r] - v.y*pi[r];
            float nr = pr[r]*c4 - pi[r]*s4;   // * e^{+i 4 th w}
            pi[r] = pi[r]*c4 + pr[r]*s4;
            pr[r] = nr;
        }
    }
    float2 b0 = rp[0];
    float2 v128 = rp[128];
    float nyq = (w & 1)? -v128.x : v128.x;
    // chains covered kx=1..128 with weight 2; Nyquist belongs with weight 1 -> subtract once
    float y = b0.x + 2.f*((acc[0]+acc[1])+(acc[2]+acc[3])) - nyq;
    y *= (1.f/16.f);
    float rho = -y;
    int hw = h*256 + w;
    float s0 = st[(size_t)(b*3)*HW + hw];
    float t = 10.f*fmaf(0.05f, rho, s0);
    float sp = fmaxf(t, 0.f) + log1pf(expf(-fabsf(t)));
    outp[(size_t)(b*3)*HW + hw] = 0.1f*sp;
    outp[(size_t)1572864 + (size_t)(b*3)*HW + hw] = rho;
}

extern "C" void kernel_launch(void* const* d_in, const int* in_sizes, int n_in,
                              void* d_out, int out_size, void* d_ws, size_t ws_size,
                              hipStream_t stream){
    const float* state = (const float*)d_in[0];
    const float* lw  = (const float*)d_in[1];
    const float* lb  = (const float*)d_in[2];
    const float* swr = (const float*)d_in[3];
    const float* swi = (const float*)d_in[4];
    const float* pww = (const float*)d_in[5];
    // d_in[6] = pw_b : cancels exactly in InstanceNorm, unused
    const float* fw1 = (const float*)d_in[7];
    const float* fb1 = (const float*)d_in[8];
    const float* fw2 = (const float*)d_in[9];
    const float* fb2 = (const float*)d_in[10];
    const float* qw1 = (const float*)d_in[11];
    const float* qb1 = (const float*)d_in[12];
    const float* qw2 = (const float*)d_in[13];
    const float* qb2 = (const float*)d_in[14];
    float* outp = (float*)d_out;
    float* ws = (float*)d_ws;

    float* x   = ws;                    // 33,554,432 f32
    float* S   = x   + 33554432;        // 16,384
    float* A   = S   + 16384;           // 262,144
    float* CS  = A   + 262144;          // 262,144
    float* J   = CS  + 262144;          // 1,048,576
    float* F1x = J   + 1048576;         // 528,384
    float* F1y = F1x + 528384;          // 528,384
    float* F2  = F1y + 528384;          // 528,384
    float* F3  = F2  + 528384;          // 528,384
    float* GH  = F3  + 528384;          // 512
    float* Wf  = GH  + 512;             // 8,192 f32 slots (2048 bf16x8 frags)
    float* T   = J;                     // alias: T dead before k_heads writes J

    hipLaunchKernelGGL(k_tables, dim3(1), dim3(256), 0, stream, GH);
    hipLaunchKernelGGL(k_prepW,  dim3(4), dim3(256), 0, stream, fw1, qw1, Wf);
    hipLaunchKernelGGL(k_lift, dim3(2048), dim3(256), 0, stream, state, lw, lb, x);
    for (int l=0; l<4; ++l){
        if (l == 0)
            hipLaunchKernelGGL(k_analysis, dim3(512), dim3(256), 0, stream, x, GH, S);
        else
            hipLaunchKernelGGL(k_analysisT, dim3(512), dim3(256), 0, stream, T, S);
        hipLaunchKernelGGL(k_mixA, dim3(512), dim3(256), 0, stream, S,
                           swr + (size_t)l*1048576, swi + (size_t)l*1048576, A);
        hipLaunchKernelGGL(k_mixB, dim3(512), dim3(256), 0, stream, A, pww + l*4096, CS);
        if (l < 3)
            hipLaunchKernelGGL((k_synth<true>),  dim3(2048), dim3(256), 0, stream, CS, x, GH, T);
        else
            hipLaunchKernelGGL((k_synth<false>), dim3(2048), dim3(256), 0, stream, CS, x, GH, T);
    }
    hipLaunchKernelGGL(k_heads, dim3(2048), dim3(256), 0, stream, x,
                       Wf, state, fb1, fw2, fb2, qb1, qw2, qb2, J, outp);
    hipLaunchKernelGGL(k_rfftW,  dim3(4096), dim3(192), 0, stream, J, F1x, F1y);
    hipLaunchKernelGGL(k_fftHdiv, dim3(1032), dim3(256), 0, stream, F1x, F1y, F2);
    hipLaunchKernelGGL(k_ifftH,  dim3(1032), dim3(256), 0, stream, F2, F3);
    hipLaunchKernelGGL(k_irfftW, dim3(2048), dim3(256), 0, stream, F3, state, outp);
}

// Round 8
// 499.824 us; speedup vs baseline: 1.4398x; 1.2504x over previous
//
#include <hip/hip_runtime.h>
#include <math.h>

#define HW 65536
#define TH_ 0.024543692606170259f  // 2*pi/256

typedef __attribute__((ext_vector_type(8))) short bf16x8;
typedef __attribute__((ext_vector_type(4))) float f32x4;

// Fast gelu: Abramowitz-Stegun 7.1.26 erf, |abs err| ~3e-7.
__device__ __forceinline__ float gelu_f(float v){
    float u = fabsf(v)*0.7071067811865476f;
    float t = __builtin_amdgcn_rcpf(fmaf(0.3275911f, u, 1.0f));
    float p = t*fmaf(t, fmaf(t, fmaf(t, fmaf(t, 1.061405429f, -1.453152027f),
                     1.421413741f), -0.284496736f), 0.254829592f);
    float e = __expf(-u*u);
    float erfu = fmaf(-p, e, 1.0f);
    float er = copysignf(erfu, v);
    return 0.5f*v*(1.0f+er);
}

__device__ __forceinline__ short f2bf(float f){
    union { float f; unsigned u; } v; v.f = f;
    unsigned r = (v.u + 0x7FFF + ((v.u >> 16) & 1)) >> 16;   // RNE
    return (short)r;
}
__device__ __forceinline__ float bf2f(short s){
    union { float f; unsigned u; } v; v.u = ((unsigned)(unsigned short)s) << 16;
    return v.f;
}

// v_cvt_pk_bf16_f32: D.lo = bf16(S0), D.hi = bf16(S1)
__device__ __forceinline__ unsigned cvt_pk_bf16(float lo, float hi){
    unsigned r;
    asm("v_cvt_pk_bf16_f32 %0, %1, %2" : "=v"(r) : "v"(lo), "v"(hi));
    return r;
}

union U8 { bf16x8 v; unsigned u[4]; };

// split 8 floats -> hi/lo bf16x8 using packed converts
__device__ __forceinline__ void split8(const float* f, bf16x8& H, bf16x8& L){
    U8 h, l;
    #pragma unroll
    for (int p=0;p<4;++p){
        float a = f[2*p], b = f[2*p+1];
        unsigned hp = cvt_pk_bf16(a, b);
        union { unsigned u; float fl; } ua, ub;
        ua.u = hp << 16; ub.u = hp & 0xffff0000u;
        h.u[p] = hp;
        l.u[p] = cvt_pk_bf16(a - ua.fl, b - ub.fl);
    }
    H = h.v; L = l.v;
}

// GH[h] = sum_{ky<16} e^{-2pi i ky h/256};
// K[d] = -(1/128) sum_{k=1..127} k*sin(2pi k d/256)   (spectral-derivative kernel)
// Q[d] =  (1/128) sum_{k=1..127}   sin(2pi k d/256)   (Nyquist-correction kernel)
__global__ void k_tables(float* __restrict__ GH, float* __restrict__ KQ){
    int h = threadIdx.x;
    double gr = 0.0, gi = 0.0;
    for (int ky=0; ky<16; ++ky){
        double a = -2.0*3.14159265358979323846*(double)(ky*h)/256.0;
        gr += cos(a); gi += sin(a);
    }
    GH[2*h] = (float)gr; GH[2*h+1] = (float)gi;
    double kk = 0.0, qq = 0.0;
    for (int k=1; k<128; ++k){
        double s = sin(2.0*3.14159265358979323846*(double)(k*h)/256.0);
        kk += (double)k * s;
        qq += s;
    }
    KQ[h]     = (float)(-kk/128.0);
    KQ[256+h] = (float)( qq/128.0);
}

// Precompute split-bf16 W1 fragments for k_heads.
__global__ __launch_bounds__(256) void k_prepW(const float* __restrict__ fw1, const float* __restrict__ qw1,
                                               float* __restrict__ Wf){
    int t = blockIdx.x*256 + threadIdx.x;       // 1024 total
    int lane = t & 63, ks = (t>>6)&1, n = (t>>7)&3, ph = (t>>9)&1;
    int l15 = lane & 15, lg = lane >> 4;
    const float* w1p = ph ? qw1 : fw1;
    int oc = n*16 + l15;
    U8 h, l;
    #pragma unroll
    for (int p=0;p<4;++p){
        float a = w1p[oc*64 + ks*32 + lg*8 + 2*p];
        float b = w1p[oc*64 + ks*32 + lg*8 + 2*p+1];
        short ha = f2bf(a), hb = f2bf(b);
        h.u[p] = ((unsigned)(unsigned short)ha) | (((unsigned)(unsigned short)hb)<<16);
        short la = f2bf(a - bf2f(ha)), lb = f2bf(b - bf2f(hb));
        l.u[p] = ((unsigned)(unsigned short)la) | (((unsigned)(unsigned short)lb)<<16);
    }
    int idx = ((ph*4+n)*2+ks)*64 + lane;
    ((bf16x8*)Wf)[idx] = h.v;
    ((bf16x8*)Wf)[1024 + idx] = l.v;
}

// Fused lift + layer-0 analysis T: block=(b,c); x[b,c,h,w]=gelu(lift); T[b,c,w]=sum_h GH[h]*x
__global__ __launch_bounds__(256) void k_lift2(const float* __restrict__ st, const float* __restrict__ lw,
                                               const float* __restrict__ lb, const float* __restrict__ GH,
                                               float* __restrict__ x, float* __restrict__ T){
    int b = blockIdx.x >> 6, c = blockIdx.x & 63;
    int w = threadIdx.x;
    __shared__ float sGH[512];
    sGH[w] = GH[w]; sGH[256+w] = GH[256+w];
    __syncthreads();
    float l0 = lw[c*3], l1 = lw[c*3+1], l2 = lw[c*3+2], lbc = lb[c];
    const float* s0p = st + (size_t)(b*3)*HW;
    float* xp = x + (size_t)blockIdx.x*HW;
    float Tr = 0.f, Ti = 0.f;
    for (int h=0; h<256; ++h){
        int idx = h*256 + w;
        float v = fmaf(l0, s0p[idx], fmaf(l1, s0p[HW+idx], fmaf(l2, s0p[2*HW+idx], lbc)));
        v = gelu_f(v);
        xp[idx] = v;
        Tr = fmaf(sGH[2*h],   v, Tr);
        Ti = fmaf(sGH[2*h+1], v, Ti);
    }
    ((float2*)T)[blockIdx.x*256 + w] = make_float2(Tr, Ti);
}

// All layers: analysis from fused T[b,i,w]
__global__ __launch_bounds__(256) void k_analysisT(const float* __restrict__ T, float* __restrict__ S){
    int bi = blockIdx.x;               // b*64+i
    int w = threadIdx.x;
    float2 t = ((const float2*)T)[bi*256 + w];
    float Tr = t.x, Ti = t.y;
    float c1, s1; sincosf((float)w * TH_, &s1, &c1);
    float Sr[16], Si[16];
    float ck = 1.f, sk = 0.f;
    #pragma unroll
    for (int k=0;k<16;++k){
        Sr[k] = Tr*ck + Ti*sk;
        Si[k] = Ti*ck - Tr*sk;
        float nc = ck*c1 - sk*s1;
        sk = ck*s1 + sk*c1;
        ck = nc;
    }
    #pragma unroll
    for (int k=0;k<16;++k){
        #pragma unroll
        for (int off=32; off; off>>=1){
            Sr[k] += __shfl_xor(Sr[k], off, 64);
            Si[k] += __shfl_xor(Si[k], off, 64);
        }
    }
    __shared__ float red[4][32];
    int wv = threadIdx.x >> 6, ln = threadIdx.x & 63;
    if (ln == 0){
        #pragma unroll
        for (int k=0;k<16;++k){ red[wv][2*k] = Sr[k]; red[wv][2*k+1] = Si[k]; }
    }
    __syncthreads();
    if (threadIdx.x < 32){
        float v = red[0][threadIdx.x]+red[1][threadIdx.x]+red[2][threadIdx.x]+red[3][threadIdx.x];
        S[bi*32 + threadIdx.x] = v * (1.0f/256.0f);
    }
}

// A[b,j,km] = sum_i S[b,i,k] * (wr + i wi)[i,j,km]
__global__ __launch_bounds__(256) void k_mixA(const float* __restrict__ S, const float* __restrict__ wr,
                                              const float* __restrict__ wi, float* __restrict__ A){
    int j = blockIdx.x >> 3, b = blockIdx.x & 7;
    __shared__ float sS[2048];
    for (int t=threadIdx.x; t<2048; t+=256) sS[t] = S[b*2048 + t];
    __syncthreads();
    int km = threadIdx.x, k = km >> 4;
    float ar = 0.f, ai = 0.f;
    const float* wrp = wr + j*256 + km;
    const float* wip = wi + j*256 + km;
    #pragma unroll 4
    for (int i=0;i<64;++i){
        float wrv = wrp[i*16384];
        float wiv = wip[i*16384];
        float2 sv = ((const float2*)sS)[i*16 + k];
        ar += sv.x*wrv - sv.y*wiv;
        ai += sv.x*wiv + sv.y*wrv;
    }
    ((float2*)A)[(b*64 + j)*256 + km] = make_float2(ar, ai);
}

// c = sum_j pw[o,j]*A[b,j,km]; Parseval stats; CS = c * inv_sigma * alpha(m) / 256
__global__ __launch_bounds__(256) void k_mixB(const float* __restrict__ A, const float* __restrict__ pw,
                                              float* __restrict__ CS){
    int b = blockIdx.x >> 6, o = blockIdx.x & 63;
    int km = threadIdx.x, m = km & 15;
    const float2* Ap = (const float2*)A + b*64*256 + km;
    const float* pwp = pw + o*64;
    float cr=0.f, ci=0.f;
    #pragma unroll 4
    for (int j=0;j<64;++j){
        float p = pwp[j];
        float2 a = Ap[j*256];
        cr = fmaf(p, a.x, cr);
        ci = fmaf(p, a.y, ci);
    }
    float aw = (m==0)? 1.f : 4.f;          // alpha(m)^2
    float s = (km==0)? 0.f : aw*(cr*cr + ci*ci);
    #pragma unroll
    for (int off=32; off; off>>=1) s += __shfl_xor(s, off, 64);
    __shared__ float rsum[4];
    __shared__ float sinv;
    if ((threadIdx.x & 63) == 0) rsum[threadIdx.x>>6] = s;
    __syncthreads();
    if (threadIdx.x == 0){
        float var = (rsum[0]+rsum[1]+rsum[2]+rsum[3]) * (1.0f/131072.0f); // /(2*H*W)
        sinv = rsqrtf(var + 1e-5f);
    }
    __syncthreads();
    float alpha = (m==0)? 1.f : 2.f;
    float sc = sinv * alpha * (1.0f/256.0f);
    if (km == 0) cr = 0.f;                 // remove mean (DC real part)
    ((float2*)CS)[blockIdx.x*256 + km] = make_float2(cr*sc, ci*sc);
}

// x += gelu(irfft-ish synth); LDS-shared V; optional T-emit.
template<bool EMIT_T>
__global__ __launch_bounds__(256) void k_synth(const float* __restrict__ CS, float* __restrict__ x,
                                               const float* __restrict__ GH, float* __restrict__ T){
    int bo = blockIdx.x >> 2, wt = blockIdx.x & 3;
    int lane = threadIdx.x & 63, wv = threadIdx.x >> 6;
    int w = wt*64 + lane;
    __shared__ float sGH[512];
    __shared__ float2 sV[16][64];
    if (EMIT_T){
        sGH[threadIdx.x] = GH[threadIdx.x];
        sGH[256+threadIdx.x] = GH[256+threadIdx.x];
    }
    const float2* cs = (const float2*)CS + bo*256;
    {   // phase A: thread computes V[k] for k in [4*wv, 4*wv+4)
        float Vr[4] = {0.f,0.f,0.f,0.f}, Vi[4] = {0.f,0.f,0.f,0.f};
        float stepc, steps; sincosf((float)w*TH_, &steps, &stepc);
        float pc = 1.f, ps = 0.f;          // e^{+i m th w}
        for (int m=0;m<16;++m){
            #pragma unroll
            for (int kk=0;kk<4;++kk){
                float2 a = cs[(wv*4+kk)*16 + m];
                Vr[kk] += a.x*pc - a.y*ps;
                Vi[kk] += a.x*ps + a.y*pc;
            }
            float nc = pc*stepc - ps*steps;
            ps = pc*steps + ps*stepc;
            pc = nc;
        }
        #pragma unroll
        for (int kk=0;kk<4;++kk) sV[wv*4+kk][lane] = make_float2(Vr[kk], Vi[kk]);
    }
    __syncthreads();
    int h0 = wv*16;
    float rc[16], rs[16], qr[16], qi[16];
    #pragma unroll
    for (int k=0;k<16;++k){
        float2 v = sV[k][lane];
        sincosf((float)k*TH_, &rs[k], &rc[k]);
        float c0, s0; sincosf((float)(k*h0)*TH_, &s0, &c0);
        qr[k] = v.x*c0 - v.y*s0;       // q = V * e^{+i th k h0}
        qi[k] = v.x*s0 + v.y*c0;
    }
    float* xp = x + ((size_t)bo << 16);
    float Tr = 0.f, Ti = 0.f;
    for (int i=0;i<16;++i){
        float y0=0.f,y1=0.f,y2=0.f,y3=0.f;
        #pragma unroll
        for (int k=0;k<16;++k){
            float re = qr[k], im = qi[k];
            y0 += re;                                   // h
            if ((k&3)==0)      { y1 += re; y2 += re; y3 += re; }   // *i^k, *(-1)^k, *(-i)^k
            else if ((k&3)==1) { y1 -= im; y2 -= re; y3 += im; }
            else if ((k&3)==2) { y1 -= re; y2 += re; y3 -= re; }
            else               { y1 += im; y2 -= re; y3 -= im; }
        }
        #pragma unroll
        for (int k=1;k<16;++k){
            float nr = qr[k]*rc[k] - qi[k]*rs[k];
            qi[k]    = qr[k]*rs[k] + qi[k]*rc[k];
            qr[k] = nr;
        }
        int p0 = (h0+i)*256 + w;
        float x0 = xp[p0], x1 = xp[p0+16384], x2 = xp[p0+32768], x3 = xp[p0+49152];
        float n0 = gelu_f(y0) + x0;
        float n1 = gelu_f(y1) + x1;
        float n2 = gelu_f(y2) + x2;
        float n3 = gelu_f(y3) + x3;
        xp[p0]       = n0;
        xp[p0+16384] = n1;
        xp[p0+32768] = n2;
        xp[p0+49152] = n3;
        if (EMIT_T){
            int h = h0+i;
            Tr = fmaf(sGH[2*h],     n0, Tr);  Ti = fmaf(sGH[2*h+1],     n0, Ti);
            Tr = fmaf(sGH[2*h+128], n1, Tr);  Ti = fmaf(sGH[2*h+129],   n1, Ti);
            Tr = fmaf(sGH[2*h+256], n2, Tr);  Ti = fmaf(sGH[2*h+257],   n2, Ti);
            Tr = fmaf(sGH[2*h+384], n3, Tr);  Ti = fmaf(sGH[2*h+385],   n3, Ti);
        }
    }
    if (EMIT_T){
        __shared__ float2 tpart[4][64];
        tpart[wv][lane] = make_float2(Tr, Ti);
        __syncthreads();
        if (wv == 0){
            float2 a = tpart[0][lane], b2 = tpart[1][lane];
            float2 c = tpart[2][lane], d = tpart[3][lane];
            ((float2*)T)[bo*256 + w] = make_float2(a.x+b2.x+c.x+d.x, a.y+b2.y+c.y+d.y);
        }
    }
}

// MFMA heads; Wf staged via LDS; ph=1 writes final P outputs directly.
__global__ __launch_bounds__(256) void k_heads(const float* __restrict__ x,
        const float* __restrict__ Wf, const float* __restrict__ st,
        const float* __restrict__ fb1, const float* __restrict__ fw2, const float* __restrict__ fb2,
        const float* __restrict__ qb1, const float* __restrict__ qw2, const float* __restrict__ qb2,
        float* __restrict__ J, float* __restrict__ outp){
    __shared__ bf16x8 sWf[2048];       // 32 KB: full split-bf16 W1 fragment table
    for (int t = threadIdx.x; t < 2048; t += 256)
        sWf[t] = ((const bf16x8*)Wf)[t];
    __syncthreads();

    int wv = threadIdx.x >> 6, lane = threadIdx.x & 63;
    int l15 = lane & 15, lg = lane >> 4;
    int px0 = blockIdx.x*256 + wv*64;
    int b = px0 >> 16;
    int hwbase = px0 & (HW-1);
    const float* xb = x + (size_t)b*64*HW;

    // A fragments: 4 M-tiles x 2 k-steps, hi/lo bf16 via cvt_pk
    bf16x8 Ahi[4][2], Alo[4][2];
    #pragma unroll
    for (int mt=0; mt<4; ++mt){
        int px = hwbase + mt*16 + l15;
        #pragma unroll
        for (int ks=0; ks<2; ++ks){
            float f[8];
            #pragma unroll
            for (int j=0; j<8; ++j)
                f[j] = xb[(size_t)((ks*32 + lg*8 + j))*HW + px];
            split8(f, Ahi[mt][ks], Alo[mt][ks]);
        }
    }

    #pragma unroll
    for (int ph=0; ph<2; ++ph){
        const float* b1p = ph ? qb1 : fb1;
        const float* w2p = ph ? qw2 : fw2;
        const float* b2p = ph ? qb2 : fb2;

        float p0[16], p1[16];
        #pragma unroll
        for (int t=0;t<16;++t){ p0[t]=0.f; p1[t]=0.f; }

        for (int n=0; n<4; ++n){
            int oc = n*16 + l15;
            float bias = b1p[oc];
            float w2a = w2p[oc], w2b = w2p[64+oc];
            int base = ((ph*4+n)*2)*64 + lane;
            bf16x8 Bhi0 = sWf[base];
            bf16x8 Bhi1 = sWf[base + 64];
            bf16x8 Blo0 = sWf[1024 + base];
            bf16x8 Blo1 = sWf[1024 + base + 64];
            #pragma unroll
            for (int mt=0; mt<4; ++mt){
                f32x4 d = {0.f,0.f,0.f,0.f};
                d = __builtin_amdgcn_mfma_f32_16x16x32_bf16(Ahi[mt][0], Bhi0, d, 0,0,0);
                d = __builtin_amdgcn_mfma_f32_16x16x32_bf16(Ahi[mt][0], Blo0, d, 0,0,0);
                d = __builtin_amdgcn_mfma_f32_16x16x32_bf16(Alo[mt][0], Bhi0, d, 0,0,0);
                d = __builtin_amdgcn_mfma_f32_16x16x32_bf16(Ahi[mt][1], Bhi1, d, 0,0,0);
                d = __builtin_amdgcn_mfma_f32_16x16x32_bf16(Ahi[mt][1], Blo1, d, 0,0,0);
                d = __builtin_amdgcn_mfma_f32_16x16x32_bf16(Alo[mt][1], Bhi1, d, 0,0,0);
                #pragma unroll
                for (int r=0;r<4;++r){
                    float g = gelu_f(d[r] + bias);
                    p0[mt*4+r] = fmaf(w2a, g, p0[mt*4+r]);
                    p1[mt*4+r] = fmaf(w2b, g, p1[mt*4+r]);
                }
            }
        }
        #pragma unroll
        for (int t=0;t<16;++t){
            #pragma unroll
            for (int off=1; off<16; off<<=1){
                p0[t] += __shfl_xor(p0[t], off, 64);
                p1[t] += __shfl_xor(p1[t], off, 64);
            }
        }
        float bo0 = b2p[0], bo1 = b2p[1];
        if (ph == 0){
            if (l15 == 0){
                float* plane = J + ((size_t)(b*2 + 0))*HW;
                #pragma unroll
                for (int mt=0; mt<4; ++mt){
                    int px = hwbase + mt*16 + lg*4;
                    float4 v; v.x=p0[mt*4+0]+bo0; v.y=p0[mt*4+1]+bo0; v.z=p0[mt*4+2]+bo0; v.w=p0[mt*4+3]+bo0;
                    *(float4*)(plane + px) = v;
                }
            } else if (l15 == 1){
                float* plane = J + ((size_t)(b*2 + 1))*HW;
                #pragma unroll
                for (int mt=0; mt<4; ++mt){
                    int px = hwbase + mt*16 + lg*4;
                    float4 v; v.x=p1[mt*4+0]+bo1; v.y=p1[mt*4+1]+bo1; v.z=p1[mt*4+2]+bo1; v.w=p1[mt*4+3]+bo1;
                    *(float4*)(plane + px) = v;
                }
            }
        } else {
            if (l15 < 2){
                const float* pv = (l15==0)? p0 : p1;
                float bN = (l15==0)? bo0 : bo1;
                const float* plane_st  = st   + ((size_t)(b*3+1+l15))*HW;
                float* plane_pred      = outp + ((size_t)(b*3+1+l15))*HW;
                float* plane_dt        = outp + 1572864 + ((size_t)(b*3+1+l15))*HW;
                #pragma unroll
                for (int mt=0; mt<4; ++mt){
                    int px = hwbase + mt*16 + lg*4;
                    float4 sv = *(const float4*)(plane_st + px);
                    float4 dt, pd;
                    dt.x = pv[mt*4+0]+bN; dt.y = pv[mt*4+1]+bN;
                    dt.z = pv[mt*4+2]+bN; dt.w = pv[mt*4+3]+bN;
                    pd.x = fmaf(0.05f, dt.x, sv.x); pd.y = fmaf(0.05f, dt.y, sv.y);
                    pd.z = fmaf(0.05f, dt.z, sv.z); pd.w = fmaf(0.05f, dt.w, sv.w);
                    *(float4*)(plane_pred + px) = pd;
                    *(float4*)(plane_dt + px)   = dt;
                }
            }
        }
    }
}

// Divergence via real circular convolution (FFT-free; operator-identical to irfft2(i k rfft2)).
// k_convH: Dx[b,h,w] = sum_h' K[(h-h')&255]*Jx[b,h',w]; r[b,w] = sum_h (-1)^h Jx[b,h,w]
__global__ __launch_bounds__(256) void k_convH(const float* __restrict__ J, const float* __restrict__ KQ,
                                               float* __restrict__ Dx, float* __restrict__ r){
    int b = blockIdx.x >> 5, wt = blockIdx.x & 31;   // 8-wide w tiles
    int w0 = wt*8;
    __shared__ float tile[256][12];                  // pad 12 -> b128-aligned rows, spread banks
    __shared__ float sK[256];
    int t = threadIdx.x;
    sK[t] = KQ[t];
    {
        const float* rp = J + (size_t)(b*2)*HW + t*256 + w0;
        float4 a = *(const float4*)rp;
        float4 bb = *(const float4*)(rp+4);
        tile[t][0]=a.x;  tile[t][1]=a.y;  tile[t][2]=a.z;  tile[t][3]=a.w;
        tile[t][4]=bb.x; tile[t][5]=bb.y; tile[t][6]=bb.z; tile[t][7]=bb.w;
    }
    __syncthreads();
    if (t < 8){
        float acc = 0.f;
        for (int h=0; h<256; ++h) acc += (h & 1)? -tile[h][t] : tile[h][t];
        r[b*256 + w0 + t] = acc;
    }
    float o[8] = {0.f,0.f,0.f,0.f,0.f,0.f,0.f,0.f};
    for (int hp=0; hp<256; ++hp){
        float k = sK[(t - hp) & 255];
        float4 ra = *(const float4*)&tile[hp][0];   // broadcast reads
        float4 rb = *(const float4*)&tile[hp][4];
        o[0]=fmaf(k, ra.x, o[0]); o[1]=fmaf(k, ra.y, o[1]);
        o[2]=fmaf(k, ra.z, o[2]); o[3]=fmaf(k, ra.w, o[3]);
        o[4]=fmaf(k, rb.x, o[4]); o[5]=fmaf(k, rb.y, o[5]);
        o[6]=fmaf(k, rb.z, o[6]); o[7]=fmaf(k, rb.w, o[7]);
    }
    float* dp = Dx + (size_t)b*HW + t*256 + w0;
    float4 v0; v0.x=o[0]; v0.y=o[1]; v0.z=o[2]; v0.w=o[3];
    float4 v1; v1.x=o[4]; v1.y=o[5]; v1.z=o[6]; v1.w=o[7];
    *(float4*)dp = v0;
    *(float4*)(dp+4) = v1;
}

// k_convW: dt_rho = -(Dx + conv_w(K,Jy) + 0.5*(-1)^h * conv_w(Q,r)); write rho outputs.
__global__ __launch_bounds__(256) void k_convW(const float* __restrict__ J, const float* __restrict__ KQ,
                                               const float* __restrict__ Dx, const float* __restrict__ r,
                                               const float* __restrict__ st, float* __restrict__ outp){
    int b = blockIdx.x >> 5, ht = blockIdx.x & 31;   // 8-row h tiles
    int h0 = ht*8;
    __shared__ float rows[8][256];
    __shared__ float sr[256], sK[256], sQ[256];
    int t = threadIdx.x;
    sK[t] = KQ[t];
    sQ[t] = KQ[256+t];
    sr[t] = r[b*256 + t];
    const float* jy = J + (size_t)(b*2+1)*HW;
    #pragma unroll
    for (int i=0;i<8;++i) rows[i][t] = jy[(h0+i)*256 + t];
    __syncthreads();
    float P = 0.f;
    float cv[8] = {0.f,0.f,0.f,0.f,0.f,0.f,0.f,0.f};
    for (int wp=0; wp<256; ++wp){
        int d = (t - wp) & 255;
        float kk = sK[d];
        P = fmaf(sQ[d], sr[wp], P);
        #pragma unroll
        for (int i=0;i<8;++i) cv[i] = fmaf(kk, rows[i][wp], cv[i]);
    }
    const float* s0p = st + (size_t)(b*3)*HW;
    const float* dxp = Dx + (size_t)b*HW;
    float* o_rho = outp + (size_t)(b*3)*HW;
    float* o_dt  = outp + 1572864 + (size_t)(b*3)*HW;
    #pragma unroll
    for (int i=0;i<8;++i){
        int h = h0 + i;
        int idx = h*256 + t;
        float corr = ((h & 1)? -0.5f : 0.5f) * P;
        float rho = -(dxp[idx] + cv[i] + corr);
        float tt = 10.f*fmaf(0.05f, rho, s0p[idx]);
        float sp = fmaxf(tt, 0.f) + log1pf(expf(-fabsf(tt)));
        o_rho[idx] = 0.1f*sp;
        o_dt[idx]  = rho;
    }
}

extern "C" void kernel_launch(void* const* d_in, const int* in_sizes, int n_in,
                              void* d_out, int out_size, void* d_ws, size_t ws_size,
                              hipStream_t stream){
    const float* state = (const float*)d_in[0];
    const float* lw  = (const float*)d_in[1];
    const float* lb  = (const float*)d_in[2];
    const float* swr = (const float*)d_in[3];
    const float* swi = (const float*)d_in[4];
    const float* pww = (const float*)d_in[5];
    // d_in[6] = pw_b : cancels exactly in InstanceNorm, unused
    const float* fw1 = (const float*)d_in[7];
    const float* fb1 = (const float*)d_in[8];
    const float* fw2 = (const float*)d_in[9];
    const float* fb2 = (const float*)d_in[10];
    const float* qw1 = (const float*)d_in[11];
    const float* qb1 = (const float*)d_in[12];
    const float* qw2 = (const float*)d_in[13];
    const float* qb2 = (const float*)d_in[14];
    float* outp = (float*)d_out;
    float* ws = (float*)d_ws;

    float* x   = ws;                    // 33,554,432 f32
    float* S   = x   + 33554432;        // 16,384
    float* A   = S   + 16384;           // 262,144
    float* CS  = A   + 262144;          // 262,144
    float* J   = CS  + 262144;          // 1,048,576 (Jx/Jy planes per b)
    float* Dx  = J   + 1048576;         // 524,288
    float* rr  = Dx  + 524288;          // 2,048
    float* GH  = rr  + 2048;            // 512
    float* KQ  = GH  + 512;             // 512
    float* Wf  = KQ  + 512;             // 8,192 f32 slots (2048 bf16x8 frags)
    float* T   = J;                     // alias: T dead before k_heads writes J

    hipLaunchKernelGGL(k_tables, dim3(1), dim3(256), 0, stream, GH, KQ);
    hipLaunchKernelGGL(k_prepW,  dim3(4), dim3(256), 0, stream, fw1, qw1, Wf);
    hipLaunchKernelGGL(k_lift2,  dim3(512), dim3(256), 0, stream, state, lw, lb, GH, x, T);
    for (int l=0; l<4; ++l){
        hipLaunchKernelGGL(k_analysisT, dim3(512), dim3(256), 0, stream, T, S);
        hipLaunchKernelGGL(k_mixA, dim3(512), dim3(256), 0, stream, S,
                           swr + (size_t)l*1048576, swi + (size_t)l*1048576, A);
        hipLaunchKernelGGL(k_mixB, dim3(512), dim3(256), 0, stream, A, pww + l*4096, CS);
        if (l < 3)
            hipLaunchKernelGGL((k_synth<true>),  dim3(2048), dim3(256), 0, stream, CS, x, GH, T);
        else
            hipLaunchKernelGGL((k_synth<false>), dim3(2048), dim3(256), 0, stream, CS, x, GH, T);
    }
    hipLaunchKernelGGL(k_heads, dim3(2048), dim3(256), 0, stream, x,
                       Wf, state, fb1, fw2, fb2, qb1, qw2, qb2, J, outp);
    hipLaunchKernelGGL(k_convH, dim3(256), dim3(256), 0, stream, J, KQ, Dx, rr);
    hipLaunchKernelGGL(k_convW, dim3(256), dim3(256), 0, stream, J, KQ, Dx, rr, state, outp);
}

// Round 9
// 482.206 us; speedup vs baseline: 1.4924x; 1.0365x over previous
//
#include <hip/hip_runtime.h>
#include <math.h>

#define HW 65536
#define TH_ 0.024543692606170259f  // 2*pi/256

typedef __attribute__((ext_vector_type(8))) short bf16x8;
typedef __attribute__((ext_vector_type(4))) float f32x4;

// Fast gelu: Abramowitz-Stegun 7.1.26 erf, |abs err| ~3e-7.
__device__ __forceinline__ float gelu_f(float v){
    float u = fabsf(v)*0.7071067811865476f;
    float t = __builtin_amdgcn_rcpf(fmaf(0.3275911f, u, 1.0f));
    float p = t*fmaf(t, fmaf(t, fmaf(t, fmaf(t, 1.061405429f, -1.453152027f),
                     1.421413741f), -0.284496736f), 0.254829592f);
    float e = __expf(-u*u);
    float erfu = fmaf(-p, e, 1.0f);
    float er = copysignf(erfu, v);
    return 0.5f*v*(1.0f+er);
}

__device__ __forceinline__ short f2bf(float f){
    union { float f; unsigned u; } v; v.f = f;
    unsigned r = (v.u + 0x7FFF + ((v.u >> 16) & 1)) >> 16;   // RNE
    return (short)r;
}
__device__ __forceinline__ float bf2f(short s){
    union { float f; unsigned u; } v; v.u = ((unsigned)(unsigned short)s) << 16;
    return v.f;
}

// v_cvt_pk_bf16_f32: D.lo = bf16(S0), D.hi = bf16(S1)
__device__ __forceinline__ unsigned cvt_pk_bf16(float lo, float hi){
    unsigned r;
    asm("v_cvt_pk_bf16_f32 %0, %1, %2" : "=v"(r) : "v"(lo), "v"(hi));
    return r;
}

union U8 { bf16x8 v; unsigned u[4]; };

// split 8 floats -> hi/lo bf16x8 using packed converts
__device__ __forceinline__ void split8(const float* f, bf16x8& H, bf16x8& L){
    U8 h, l;
    #pragma unroll
    for (int p=0;p<4;++p){
        float a = f[2*p], b = f[2*p+1];
        unsigned hp = cvt_pk_bf16(a, b);
        union { unsigned u; float fl; } ua, ub;
        ua.u = hp << 16; ub.u = hp & 0xffff0000u;
        h.u[p] = hp;
        l.u[p] = cvt_pk_bf16(a - ua.fl, b - ub.fl);
    }
    H = h.v; L = l.v;
}

// Merged init: blocks 0-3 = prepW fragments, block 4 = GH/KQ tables.
__global__ __launch_bounds__(256) void k_init(const float* __restrict__ fw1, const float* __restrict__ qw1,
                                              float* __restrict__ Wf, float* __restrict__ GH,
                                              float* __restrict__ KQ){
    if (blockIdx.x == 4){
        int h = threadIdx.x;
        double gr = 0.0, gi = 0.0;
        for (int ky=0; ky<16; ++ky){
            double a = -2.0*3.14159265358979323846*(double)(ky*h)/256.0;
            gr += cos(a); gi += sin(a);
        }
        GH[2*h] = (float)gr; GH[2*h+1] = (float)gi;
        double kk = 0.0, qq = 0.0;
        for (int k=1; k<128; ++k){
            double s = sin(2.0*3.14159265358979323846*(double)(k*h)/256.0);
            kk += (double)k * s;
            qq += s;
        }
        KQ[h]     = (float)(-kk/128.0);
        KQ[256+h] = (float)( qq/128.0);
        return;
    }
    int t = blockIdx.x*256 + threadIdx.x;       // 1024 total
    int lane = t & 63, ks = (t>>6)&1, n = (t>>7)&3, ph = (t>>9)&1;
    int l15 = lane & 15, lg = lane >> 4;
    const float* w1p = ph ? qw1 : fw1;
    int oc = n*16 + l15;
    U8 h, l;
    #pragma unroll
    for (int p=0;p<4;++p){
        float a = w1p[oc*64 + ks*32 + lg*8 + 2*p];
        float b = w1p[oc*64 + ks*32 + lg*8 + 2*p+1];
        short ha = f2bf(a), hb = f2bf(b);
        h.u[p] = ((unsigned)(unsigned short)ha) | (((unsigned)(unsigned short)hb)<<16);
        short la = f2bf(a - bf2f(ha)), lb = f2bf(b - bf2f(hb));
        l.u[p] = ((unsigned)(unsigned short)la) | (((unsigned)(unsigned short)lb)<<16);
    }
    int idx = ((ph*4+n)*2+ks)*64 + lane;
    ((bf16x8*)Wf)[idx] = h.v;
    ((bf16x8*)Wf)[1024 + idx] = l.v;
}

// Fused lift + layer-0 analysis; 1024 threads: (w, hq) with hq = 64-row quarter.
// R8's 256-thread version was parallelism-starved (512 blocks = 25% max occupancy, 77us).
__global__ __launch_bounds__(1024) void k_lift2(const float* __restrict__ st, const float* __restrict__ lw,
                                                const float* __restrict__ lb, const float* __restrict__ GH,
                                                float* __restrict__ x, float* __restrict__ T){
    int b = blockIdx.x >> 6, c = blockIdx.x & 63;
    int t = threadIdx.x;
    int w = t & 255, hq = t >> 8;
    __shared__ float sGH[512];
    __shared__ float2 tp[4][256];
    if (t < 512) sGH[t] = GH[t];
    __syncthreads();
    float l0 = lw[c*3], l1 = lw[c*3+1], l2 = lw[c*3+2], lbc = lb[c];
    const float* s0p = st + (size_t)(b*3)*HW;
    float* xp = x + (size_t)blockIdx.x*HW;
    float Tr = 0.f, Ti = 0.f;
    #pragma unroll 4
    for (int i=0; i<64; ++i){
        int h = hq*64 + i;
        int idx = h*256 + w;
        float v = fmaf(l0, s0p[idx], fmaf(l1, s0p[HW+idx], fmaf(l2, s0p[2*HW+idx], lbc)));
        v = gelu_f(v);
        xp[idx] = v;
        Tr = fmaf(sGH[2*h],   v, Tr);
        Ti = fmaf(sGH[2*h+1], v, Ti);
    }
    tp[hq][w] = make_float2(Tr, Ti);
    __syncthreads();
    if (hq == 0){
        float2 a = tp[0][w], b2 = tp[1][w], cc = tp[2][w], d = tp[3][w];
        ((float2*)T)[blockIdx.x*256 + w] = make_float2(a.x+b2.x+cc.x+d.x, a.y+b2.y+cc.y+d.y);
    }
}

// All layers: analysis from fused T[b,i,w]
__global__ __launch_bounds__(256) void k_analysisT(const float* __restrict__ T, float* __restrict__ S){
    int bi = blockIdx.x;               // b*64+i
    int w = threadIdx.x;
    float2 t = ((const float2*)T)[bi*256 + w];
    float Tr = t.x, Ti = t.y;
    float c1, s1; sincosf((float)w * TH_, &s1, &c1);
    float Sr[16], Si[16];
    float ck = 1.f, sk = 0.f;
    #pragma unroll
    for (int k=0;k<16;++k){
        Sr[k] = Tr*ck + Ti*sk;
        Si[k] = Ti*ck - Tr*sk;
        float nc = ck*c1 - sk*s1;
        sk = ck*s1 + sk*c1;
        ck = nc;
    }
    #pragma unroll
    for (int k=0;k<16;++k){
        #pragma unroll
        for (int off=32; off; off>>=1){
            Sr[k] += __shfl_xor(Sr[k], off, 64);
            Si[k] += __shfl_xor(Si[k], off, 64);
        }
    }
    __shared__ float red[4][32];
    int wv = threadIdx.x >> 6, ln = threadIdx.x & 63;
    if (ln == 0){
        #pragma unroll
        for (int k=0;k<16;++k){ red[wv][2*k] = Sr[k]; red[wv][2*k+1] = Si[k]; }
    }
    __syncthreads();
    if (threadIdx.x < 32){
        float v = red[0][threadIdx.x]+red[1][threadIdx.x]+red[2][threadIdx.x]+red[3][threadIdx.x];
        S[bi*32 + threadIdx.x] = v * (1.0f/256.0f);
    }
}

// A[b,j,km] = sum_i S[b,i,k] * (wr + i wi)[i,j,km]
__global__ __launch_bounds__(256) void k_mixA(const float* __restrict__ S, const float* __restrict__ wr,
                                              const float* __restrict__ wi, float* __restrict__ A){
    int j = blockIdx.x >> 3, b = blockIdx.x & 7;
    __shared__ float sS[2048];
    for (int t=threadIdx.x; t<2048; t+=256) sS[t] = S[b*2048 + t];
    __syncthreads();
    int km = threadIdx.x, k = km >> 4;
    float ar = 0.f, ai = 0.f;
    const float* wrp = wr + j*256 + km;
    const float* wip = wi + j*256 + km;
    #pragma unroll 4
    for (int i=0;i<64;++i){
        float wrv = wrp[i*16384];
        float wiv = wip[i*16384];
        float2 sv = ((const float2*)sS)[i*16 + k];
        ar += sv.x*wrv - sv.y*wiv;
        ai += sv.x*wiv + sv.y*wrv;
    }
    ((float2*)A)[(b*64 + j)*256 + km] = make_float2(ar, ai);
}

// c = sum_j pw[o,j]*A[b,j,km]; Parseval stats; CS = c * inv_sigma * alpha(m) / 256
__global__ __launch_bounds__(256) void k_mixB(const float* __restrict__ A, const float* __restrict__ pw,
                                              float* __restrict__ CS){
    int b = blockIdx.x >> 6, o = blockIdx.x & 63;
    int km = threadIdx.x, m = km & 15;
    const float2* Ap = (const float2*)A + b*64*256 + km;
    const float* pwp = pw + o*64;
    float cr=0.f, ci=0.f;
    #pragma unroll 4
    for (int j=0;j<64;++j){
        float p = pwp[j];
        float2 a = Ap[j*256];
        cr = fmaf(p, a.x, cr);
        ci = fmaf(p, a.y, ci);
    }
    float aw = (m==0)? 1.f : 4.f;          // alpha(m)^2
    float s = (km==0)? 0.f : aw*(cr*cr + ci*ci);
    #pragma unroll
    for (int off=32; off; off>>=1) s += __shfl_xor(s, off, 64);
    __shared__ float rsum[4];
    __shared__ float sinv;
    if ((threadIdx.x & 63) == 0) rsum[threadIdx.x>>6] = s;
    __syncthreads();
    if (threadIdx.x == 0){
        float var = (rsum[0]+rsum[1]+rsum[2]+rsum[3]) * (1.0f/131072.0f); // /(2*H*W)
        sinv = rsqrtf(var + 1e-5f);
    }
    __syncthreads();
    float alpha = (m==0)? 1.f : 2.f;
    float sc = sinv * alpha * (1.0f/256.0f);
    if (km == 0) cr = 0.f;                 // remove mean (DC real part)
    ((float2*)CS)[blockIdx.x*256 + km] = make_float2(cr*sc, ci*sc);
}

// x += gelu(irfft-ish synth); LDS-shared V; optional T-emit.
template<bool EMIT_T>
__global__ __launch_bounds__(256) void k_synth(const float* __restrict__ CS, float* __restrict__ x,
                                               const float* __restrict__ GH, float* __restrict__ T){
    int bo = blockIdx.x >> 2, wt = blockIdx.x & 3;
    int lane = threadIdx.x & 63, wv = threadIdx.x >> 6;
    int w = wt*64 + lane;
    __shared__ float sGH[512];
    __shared__ float2 sV[16][64];
    if (EMIT_T){
        sGH[threadIdx.x] = GH[threadIdx.x];
        sGH[256+threadIdx.x] = GH[256+threadIdx.x];
    }
    const float2* cs = (const float2*)CS + bo*256;
    {   // phase A: thread computes V[k] for k in [4*wv, 4*wv+4)
        float Vr[4] = {0.f,0.f,0.f,0.f}, Vi[4] = {0.f,0.f,0.f,0.f};
        float stepc, steps; sincosf((float)w*TH_, &steps, &stepc);
        float pc = 1.f, ps = 0.f;          // e^{+i m th w}
        for (int m=0;m<16;++m){
            #pragma unroll
            for (int kk=0;kk<4;++kk){
                float2 a = cs[(wv*4+kk)*16 + m];
                Vr[kk] += a.x*pc - a.y*ps;
                Vi[kk] += a.x*ps + a.y*pc;
            }
            float nc = pc*stepc - ps*steps;
            ps = pc*steps + ps*stepc;
            pc = nc;
        }
        #pragma unroll
        for (int kk=0;kk<4;++kk) sV[wv*4+kk][lane] = make_float2(Vr[kk], Vi[kk]);
    }
    __syncthreads();
    int h0 = wv*16;
    float rc[16], rs[16], qr[16], qi[16];
    #pragma unroll
    for (int k=0;k<16;++k){
        float2 v = sV[k][lane];
        sincosf((float)k*TH_, &rs[k], &rc[k]);
        float c0, s0; sincosf((float)(k*h0)*TH_, &s0, &c0);
        qr[k] = v.x*c0 - v.y*s0;       // q = V * e^{+i th k h0}
        qi[k] = v.x*s0 + v.y*c0;
    }
    float* xp = x + ((size_t)bo << 16);
    float Tr = 0.f, Ti = 0.f;
    for (int i=0;i<16;++i){
        float y0=0.f,y1=0.f,y2=0.f,y3=0.f;
        #pragma unroll
        for (int k=0;k<16;++k){
            float re = qr[k], im = qi[k];
            y0 += re;                                   // h
            if ((k&3)==0)      { y1 += re; y2 += re; y3 += re; }   // *i^k, *(-1)^k, *(-i)^k
            else if ((k&3)==1) { y1 -= im; y2 -= re; y3 += im; }
            else if ((k&3)==2) { y1 -= re; y2 += re; y3 -= re; }
            else               { y1 += im; y2 -= re; y3 -= im; }
        }
        #pragma unroll
        for (int k=1;k<16;++k){
            float nr = qr[k]*rc[k] - qi[k]*rs[k];
            qi[k]    = qr[k]*rs[k] + qi[k]*rc[k];
            qr[k] = nr;
        }
        int p0 = (h0+i)*256 + w;
        float x0 = xp[p0], x1 = xp[p0+16384], x2 = xp[p0+32768], x3 = xp[p0+49152];
        float n0 = gelu_f(y0) + x0;
        float n1 = gelu_f(y1) + x1;
        float n2 = gelu_f(y2) + x2;
        float n3 = gelu_f(y3) + x3;
        xp[p0]       = n0;
        xp[p0+16384] = n1;
        xp[p0+32768] = n2;
        xp[p0+49152] = n3;
        if (EMIT_T){
            int h = h0+i;
            Tr = fmaf(sGH[2*h],     n0, Tr);  Ti = fmaf(sGH[2*h+1],     n0, Ti);
            Tr = fmaf(sGH[2*h+128], n1, Tr);  Ti = fmaf(sGH[2*h+129],   n1, Ti);
            Tr = fmaf(sGH[2*h+256], n2, Tr);  Ti = fmaf(sGH[2*h+257],   n2, Ti);
            Tr = fmaf(sGH[2*h+384], n3, Tr);  Ti = fmaf(sGH[2*h+385],   n3, Ti);
        }
    }
    if (EMIT_T){
        __shared__ float2 tpart[4][64];
        tpart[wv][lane] = make_float2(Tr, Ti);
        __syncthreads();
        if (wv == 0){
            float2 a = tpart[0][lane], b2 = tpart[1][lane];
            float2 c = tpart[2][lane], d = tpart[3][lane];
            ((float2*)T)[bo*256 + w] = make_float2(a.x+b2.x+c.x+d.x, a.y+b2.y+c.y+d.y);
        }
    }
}

// MFMA heads; Wf staged via LDS; mt=2 (32 px/wave) to cut VGPR (R8: 116 VGPR -> occ 20%).
// ph=1 writes final P outputs directly.
__global__ __launch_bounds__(256) void k_heads(const float* __restrict__ x,
        const float* __restrict__ Wf, const float* __restrict__ st,
        const float* __restrict__ fb1, const float* __restrict__ fw2, const float* __restrict__ fb2,
        const float* __restrict__ qb1, const float* __restrict__ qw2, const float* __restrict__ qb2,
        float* __restrict__ J, float* __restrict__ outp){
    __shared__ bf16x8 sWf[2048];       // 32 KB: full split-bf16 W1 fragment table
    for (int t = threadIdx.x; t < 2048; t += 256)
        sWf[t] = ((const bf16x8*)Wf)[t];
    __syncthreads();

    int wv = threadIdx.x >> 6, lane = threadIdx.x & 63;
    int l15 = lane & 15, lg = lane >> 4;
    int px0 = blockIdx.x*128 + wv*32;     // 32 px per wave
    int b = px0 >> 16;
    int hwbase = px0 & (HW-1);
    const float* xb = x + (size_t)b*64*HW;

    // A fragments: 2 M-tiles x 2 k-steps, hi/lo bf16 via cvt_pk
    bf16x8 Ahi[2][2], Alo[2][2];
    #pragma unroll
    for (int mt=0; mt<2; ++mt){
        int px = hwbase + mt*16 + l15;
        #pragma unroll
        for (int ks=0; ks<2; ++ks){
            float f[8];
            #pragma unroll
            for (int j=0; j<8; ++j)
                f[j] = xb[(size_t)((ks*32 + lg*8 + j))*HW + px];
            split8(f, Ahi[mt][ks], Alo[mt][ks]);
        }
    }

    #pragma unroll
    for (int ph=0; ph<2; ++ph){
        const float* b1p = ph ? qb1 : fb1;
        const float* w2p = ph ? qw2 : fw2;
        const float* b2p = ph ? qb2 : fb2;

        float p0[8], p1[8];
        #pragma unroll
        for (int t=0;t<8;++t){ p0[t]=0.f; p1[t]=0.f; }

        for (int n=0; n<4; ++n){
            int oc = n*16 + l15;
            float bias = b1p[oc];
            float w2a = w2p[oc], w2b = w2p[64+oc];
            int base = ((ph*4+n)*2)*64 + lane;
            bf16x8 Bhi0 = sWf[base];
            bf16x8 Bhi1 = sWf[base + 64];
            bf16x8 Blo0 = sWf[1024 + base];
            bf16x8 Blo1 = sWf[1024 + base + 64];
            #pragma unroll
            for (int mt=0; mt<2; ++mt){
                f32x4 d = {0.f,0.f,0.f,0.f};
                d = __builtin_amdgcn_mfma_f32_16x16x32_bf16(Ahi[mt][0], Bhi0, d, 0,0,0);
                d = __builtin_amdgcn_mfma_f32_16x16x32_bf16(Ahi[mt][0], Blo0, d, 0,0,0);
                d = __builtin_amdgcn_mfma_f32_16x16x32_bf16(Alo[mt][0], Bhi0, d, 0,0,0);
                d = __builtin_amdgcn_mfma_f32_16x16x32_bf16(Ahi[mt][1], Bhi1, d, 0,0,0);
                d = __builtin_amdgcn_mfma_f32_16x16x32_bf16(Ahi[mt][1], Blo1, d, 0,0,0);
                d = __builtin_amdgcn_mfma_f32_16x16x32_bf16(Alo[mt][1], Bhi1, d, 0,0,0);
                #pragma unroll
                for (int r=0;r<4;++r){
                    float g = gelu_f(d[r] + bias);
                    p0[mt*4+r] = fmaf(w2a, g, p0[mt*4+r]);
                    p1[mt*4+r] = fmaf(w2b, g, p1[mt*4+r]);
                }
            }
        }
        #pragma unroll
        for (int t=0;t<8;++t){
            #pragma unroll
            for (int off=1; off<16; off<<=1){
                p0[t] += __shfl_xor(p0[t], off, 64);
                p1[t] += __shfl_xor(p1[t], off, 64);
            }
        }
        float bo0 = b2p[0], bo1 = b2p[1];
        if (ph == 0){
            if (l15 == 0){
                float* plane = J + ((size_t)(b*2 + 0))*HW;
                #pragma unroll
                for (int mt=0; mt<2; ++mt){
                    int px = hwbase + mt*16 + lg*4;
                    float4 v; v.x=p0[mt*4+0]+bo0; v.y=p0[mt*4+1]+bo0; v.z=p0[mt*4+2]+bo0; v.w=p0[mt*4+3]+bo0;
                    *(float4*)(plane + px) = v;
                }
            } else if (l15 == 1){
                float* plane = J + ((size_t)(b*2 + 1))*HW;
                #pragma unroll
                for (int mt=0; mt<2; ++mt){
                    int px = hwbase + mt*16 + lg*4;
                    float4 v; v.x=p1[mt*4+0]+bo1; v.y=p1[mt*4+1]+bo1; v.z=p1[mt*4+2]+bo1; v.w=p1[mt*4+3]+bo1;
                    *(float4*)(plane + px) = v;
                }
            }
        } else {
            if (l15 < 2){
                const float* pv = (l15==0)? p0 : p1;
                float bN = (l15==0)? bo0 : bo1;
                const float* plane_st  = st   + ((size_t)(b*3+1+l15))*HW;
                float* plane_pred      = outp + ((size_t)(b*3+1+l15))*HW;
                float* plane_dt        = outp + 1572864 + ((size_t)(b*3+1+l15))*HW;
                #pragma unroll
                for (int mt=0; mt<2; ++mt){
                    int px = hwbase + mt*16 + lg*4;
                    float4 sv = *(const float4*)(plane_st + px);
                    float4 dt, pd;
                    dt.x = pv[mt*4+0]+bN; dt.y = pv[mt*4+1]+bN;
                    dt.z = pv[mt*4+2]+bN; dt.w = pv[mt*4+3]+bN;
                    pd.x = fmaf(0.05f, dt.x, sv.x); pd.y = fmaf(0.05f, dt.y, sv.y);
                    pd.z = fmaf(0.05f, dt.z, sv.z); pd.w = fmaf(0.05f, dt.w, sv.w);
                    *(float4*)(plane_pred + px) = pd;
                    *(float4*)(plane_dt + px)   = dt;
                }
            }
        }
    }
}

// Divergence via real circular convolution (FFT-free; operator-identical to irfft2(i k rfft2)).
// k_convH: Dx[b,h,w] = sum_h' K[(h-h')&255]*Jx[b,h',w]; r[b,w] = sum_h (-1)^h Jx[b,h,w]
__global__ __launch_bounds__(256) void k_convH(const float* __restrict__ J, const float* __restrict__ KQ,
                                               float* __restrict__ Dx, float* __restrict__ r){
    int b = blockIdx.x >> 5, wt = blockIdx.x & 31;   // 8-wide w tiles
    int w0 = wt*8;
    __shared__ float tile[256][12];                  // pad 12 -> spread banks
    __shared__ float sK[256];
    int t = threadIdx.x;
    sK[t] = KQ[t];
    {
        const float* rp = J + (size_t)(b*2)*HW + t*256 + w0;
        float4 a = *(const float4*)rp;
        float4 bb = *(const float4*)(rp+4);
        tile[t][0]=a.x;  tile[t][1]=a.y;  tile[t][2]=a.z;  tile[t][3]=a.w;
        tile[t][4]=bb.x; tile[t][5]=bb.y; tile[t][6]=bb.z; tile[t][7]=bb.w;
    }
    __syncthreads();
    if (t < 8){
        float acc = 0.f;
        for (int h=0; h<256; ++h) acc += (h & 1)? -tile[h][t] : tile[h][t];
        r[b*256 + w0 + t] = acc;
    }
    float o[8] = {0.f,0.f,0.f,0.f,0.f,0.f,0.f,0.f};
    for (int hp=0; hp<256; ++hp){
        float k = sK[(t - hp) & 255];
        float4 ra = *(const float4*)&tile[hp][0];   // broadcast reads
        float4 rb = *(const float4*)&tile[hp][4];
        o[0]=fmaf(k, ra.x, o[0]); o[1]=fmaf(k, ra.y, o[1]);
        o[2]=fmaf(k, ra.z, o[2]); o[3]=fmaf(k, ra.w, o[3]);
        o[4]=fmaf(k, rb.x, o[4]); o[5]=fmaf(k, rb.y, o[5]);
        o[6]=fmaf(k, rb.z, o[6]); o[7]=fmaf(k, rb.w, o[7]);
    }
    float* dp = Dx + (size_t)b*HW + t*256 + w0;
    float4 v0; v0.x=o[0]; v0.y=o[1]; v0.z=o[2]; v0.w=o[3];
    float4 v1; v1.x=o[4]; v1.y=o[5]; v1.z=o[6]; v1.w=o[7];
    *(float4*)dp = v0;
    *(float4*)(dp+4) = v1;
}

// k_convW: dt_rho = -(Dx + conv_w(K,Jy) + 0.5*(-1)^h * conv_w(Q,r)); write rho outputs.
__global__ __launch_bounds__(256) void k_convW(const float* __restrict__ J, const float* __restrict__ KQ,
                                               const float* __restrict__ Dx, const float* __restrict__ r,
                                               const float* __restrict__ st, float* __restrict__ outp){
    int b = blockIdx.x >> 5, ht = blockIdx.x & 31;   // 8-row h tiles
    int h0 = ht*8;
    __shared__ float rows[8][256];
    __shared__ float sr[256], sK[256], sQ[256];
    int t = threadIdx.x;
    sK[t] = KQ[t];
    sQ[t] = KQ[256+t];
    sr[t] = r[b*256 + t];
    const float* jy = J + (size_t)(b*2+1)*HW;
    #pragma unroll
    for (int i=0;i<8;++i) rows[i][t] = jy[(h0+i)*256 + t];
    __syncthreads();
    float P = 0.f;
    float cv[8] = {0.f,0.f,0.f,0.f,0.f,0.f,0.f,0.f};
    for (int wp=0; wp<256; ++wp){
        int d = (t - wp) & 255;
        float kk = sK[d];
        P = fmaf(sQ[d], sr[wp], P);
        #pragma unroll
        for (int i=0;i<8;++i) cv[i] = fmaf(kk, rows[i][wp], cv[i]);
    }
    const float* s0p = st + (size_t)(b*3)*HW;
    const float* dxp = Dx + (size_t)b*HW;
    float* o_rho = outp + (size_t)(b*3)*HW;
    float* o_dt  = outp + 1572864 + (size_t)(b*3)*HW;
    #pragma unroll
    for (int i=0;i<8;++i){
        int h = h0 + i;
        int idx = h*256 + t;
        float corr = ((h & 1)? -0.5f : 0.5f) * P;
        float rho = -(dxp[idx] + cv[i] + corr);
        float tt = 10.f*fmaf(0.05f, rho, s0p[idx]);
        float sp = fmaxf(tt, 0.f) + log1pf(expf(-fabsf(tt)));
        o_rho[idx] = 0.1f*sp;
        o_dt[idx]  = rho;
    }
}

extern "C" void kernel_launch(void* const* d_in, const int* in_sizes, int n_in,
                              void* d_out, int out_size, void* d_ws, size_t ws_size,
                              hipStream_t stream){
    const float* state = (const float*)d_in[0];
    const float* lw  = (const float*)d_in[1];
    const float* lb  = (const float*)d_in[2];
    const float* swr = (const float*)d_in[3];
    const float* swi = (const float*)d_in[4];
    const float* pww = (const float*)d_in[5];
    // d_in[6] = pw_b : cancels exactly in InstanceNorm, unused
    const float* fw1 = (const float*)d_in[7];
    const float* fb1 = (const float*)d_in[8];
    const float* fw2 = (const float*)d_in[9];
    const float* fb2 = (const float*)d_in[10];
    const float* qw1 = (const float*)d_in[11];
    const float* qb1 = (const float*)d_in[12];
    const float* qw2 = (const float*)d_in[13];
    const float* qb2 = (const float*)d_in[14];
    float* outp = (float*)d_out;
    float* ws = (float*)d_ws;

    float* x   = ws;                    // 33,554,432 f32
    float* S   = x   + 33554432;        // 16,384
    float* A   = S   + 16384;           // 262,144
    float* CS  = A   + 262144;          // 262,144
    float* J   = CS  + 262144;          // 1,048,576 (Jx/Jy planes per b)
    float* Dx  = J   + 1048576;         // 524,288
    float* rr  = Dx  + 524288;          // 2,048
    float* GH  = rr  + 2048;            // 512
    float* KQ  = GH  + 512;             // 512
    float* Wf  = KQ  + 512;             // 8,192 f32 slots (2048 bf16x8 frags)
    float* T   = J;                     // alias: T dead before k_heads writes J

    hipLaunchKernelGGL(k_init,  dim3(5), dim3(256), 0, stream, fw1, qw1, Wf, GH, KQ);
    hipLaunchKernelGGL(k_lift2, dim3(512), dim3(1024), 0, stream, state, lw, lb, GH, x, T);
    for (int l=0; l<4; ++l){
        hipLaunchKernelGGL(k_analysisT, dim3(512), dim3(256), 0, stream, T, S);
        hipLaunchKernelGGL(k_mixA, dim3(512), dim3(256), 0, stream, S,
                           swr + (size_t)l*1048576, swi + (size_t)l*1048576, A);
        hipLaunchKernelGGL(k_mixB, dim3(512), dim3(256), 0, stream, A, pww + l*4096, CS);
        if (l < 3)
            hipLaunchKernelGGL((k_synth<true>),  dim3(2048), dim3(256), 0, stream, CS, x, GH, T);
        else
            hipLaunchKernelGGL((k_synth<false>), dim3(2048), dim3(256), 0, stream, CS, x, GH, T);
    }
    hipLaunchKernelGGL(k_heads, dim3(4096), dim3(256), 0, stream, x,
                       Wf, state, fb1, fw2, fb2, qb1, qw2, qb2, J, outp);
    hipLaunchKernelGGL(k_convH, dim3(256), dim3(256), 0, stream, J, KQ, Dx, rr);
    hipLaunchKernelGGL(k_convW, dim3(256), dim3(256), 0, stream, J, KQ, Dx, rr, state, outp);
}

// Round 12
// 481.842 us; speedup vs baseline: 1.4936x; 1.0008x over previous
//
#include <hip/hip_runtime.h>
#include <math.h>

#define HW 65536
#define TH_ 0.024543692606170259f  // 2*pi/256

typedef __attribute__((ext_vector_type(8))) short bf16x8;
typedef __attribute__((ext_vector_type(4))) float f32x4;

// Fast gelu: Abramowitz-Stegun 7.1.26 erf, |abs err| ~3e-7.
__device__ __forceinline__ float gelu_f(float v){
    float u = fabsf(v)*0.7071067811865476f;
    float t = __builtin_amdgcn_rcpf(fmaf(0.3275911f, u, 1.0f));
    float p = t*fmaf(t, fmaf(t, fmaf(t, fmaf(t, 1.061405429f, -1.453152027f),
                     1.421413741f), -0.284496736f), 0.254829592f);
    float e = __expf(-u*u);
    float erfu = fmaf(-p, e, 1.0f);
    float er = copysignf(erfu, v);
    return 0.5f*v*(1.0f+er);
}

__device__ __forceinline__ short f2bf(float f){
    union { float f; unsigned u; } v; v.f = f;
    unsigned r = (v.u + 0x7FFF + ((v.u >> 16) & 1)) >> 16;   // RNE
    return (short)r;
}
__device__ __forceinline__ float bf2f(short s){
    union { float f; unsigned u; } v; v.u = ((unsigned)(unsigned short)s) << 16;
    return v.f;
}

// v_cvt_pk_bf16_f32: D.lo = bf16(S0), D.hi = bf16(S1)
__device__ __forceinline__ unsigned cvt_pk_bf16(float lo, float hi){
    unsigned r;
    asm("v_cvt_pk_bf16_f32 %0, %1, %2" : "=v"(r) : "v"(lo), "v"(hi));
    return r;
}

union U8 { bf16x8 v; unsigned u[4]; };

// split 8 floats -> hi/lo bf16x8 using packed converts
__device__ __forceinline__ void split8(const float* f, bf16x8& H, bf16x8& L){
    U8 h, l;
    #pragma unroll
    for (int p=0;p<4;++p){
        float a = f[2*p], b = f[2*p+1];
        unsigned hp = cvt_pk_bf16(a, b);
        union { unsigned u; float fl; } ua, ub;
        ua.u = hp << 16; ub.u = hp & 0xffff0000u;
        h.u[p] = hp;
        l.u[p] = cvt_pk_bf16(a - ua.fl, b - ub.fl);
    }
    H = h.v; L = l.v;
}

// Merged init: blocks 0-3 = prepW fragments, block 4 = GH/KQ tables.
__global__ __launch_bounds__(256) void k_init(const float* __restrict__ fw1, const float* __restrict__ qw1,
                                              float* __restrict__ Wf, float* __restrict__ GH,
                                              float* __restrict__ KQ){
    if (blockIdx.x == 4){
        int h = threadIdx.x;
        double gr = 0.0, gi = 0.0;
        for (int ky=0; ky<16; ++ky){
            double a = -2.0*3.14159265358979323846*(double)(ky*h)/256.0;
            gr += cos(a); gi += sin(a);
        }
        GH[2*h] = (float)gr; GH[2*h+1] = (float)gi;
        double kk = 0.0, qq = 0.0;
        for (int k=1; k<128; ++k){
            double s = sin(2.0*3.14159265358979323846*(double)(k*h)/256.0);
            kk += (double)k * s;
            qq += s;
        }
        KQ[h]     = (float)(-kk/128.0);
        KQ[256+h] = (float)( qq/128.0);
        return;
    }
    int t = blockIdx.x*256 + threadIdx.x;       // 1024 total
    int lane = t & 63, ks = (t>>6)&1, n = (t>>7)&3, ph = (t>>9)&1;
    int l15 = lane & 15, lg = lane >> 4;
    const float* w1p = ph ? qw1 : fw1;
    int oc = n*16 + l15;
    U8 h, l;
    #pragma unroll
    for (int p=0;p<4;++p){
        float a = w1p[oc*64 + ks*32 + lg*8 + 2*p];
        float b = w1p[oc*64 + ks*32 + lg*8 + 2*p+1];
        short ha = f2bf(a), hb = f2bf(b);
        h.u[p] = ((unsigned)(unsigned short)ha) | (((unsigned)(unsigned short)hb)<<16);
        short la = f2bf(a - bf2f(ha)), lb = f2bf(b - bf2f(hb));
        l.u[p] = ((unsigned)(unsigned short)la) | (((unsigned)(unsigned short)lb)<<16);
    }
    int idx = ((ph*4+n)*2+ks)*64 + lane;
    ((bf16x8*)Wf)[idx] = h.v;
    ((bf16x8*)Wf)[1024 + idx] = l.v;
}

// Fused lift + layer-0 analysis; 1024 threads: (w, hq) with hq = 64-row quarter.
__global__ __launch_bounds__(1024) void k_lift2(const float* __restrict__ st, const float* __restrict__ lw,
                                                const float* __restrict__ lb, const float* __restrict__ GH,
                                                float* __restrict__ x, float* __restrict__ T){
    int b = blockIdx.x >> 6, c = blockIdx.x & 63;
    int t = threadIdx.x;
    int w = t & 255, hq = t >> 8;
    __shared__ float sGH[512];
    __shared__ float2 tp[4][256];
    if (t < 512) sGH[t] = GH[t];
    __syncthreads();
    float l0 = lw[c*3], l1 = lw[c*3+1], l2 = lw[c*3+2], lbc = lb[c];
    const float* s0p = st + (size_t)(b*3)*HW;
    float* xp = x + (size_t)blockIdx.x*HW;
    float Tr = 0.f, Ti = 0.f;
    #pragma unroll 4
    for (int i=0; i<64; ++i){
        int h = hq*64 + i;
        int idx = h*256 + w;
        float v = fmaf(l0, s0p[idx], fmaf(l1, s0p[HW+idx], fmaf(l2, s0p[2*HW+idx], lbc)));
        v = gelu_f(v);
        xp[idx] = v;
        Tr = fmaf(sGH[2*h],   v, Tr);
        Ti = fmaf(sGH[2*h+1], v, Ti);
    }
    tp[hq][w] = make_float2(Tr, Ti);
    __syncthreads();
    if (hq == 0){
        float2 a = tp[0][w], b2 = tp[1][w], cc = tp[2][w], d = tp[3][w];
        ((float2*)T)[blockIdx.x*256 + w] = make_float2(a.x+b2.x+cc.x+d.x, a.y+b2.y+cc.y+d.y);
    }
}

// All layers: analysis from fused T[b,i,w]
__global__ __launch_bounds__(256) void k_analysisT(const float* __restrict__ T, float* __restrict__ S){
    int bi = blockIdx.x;               // b*64+i
    int w = threadIdx.x;
    float2 t = ((const float2*)T)[bi*256 + w];
    float Tr = t.x, Ti = t.y;
    float c1, s1; sincosf((float)w * TH_, &s1, &c1);
    float Sr[16], Si[16];
    float ck = 1.f, sk = 0.f;
    #pragma unroll
    for (int k=0;k<16;++k){
        Sr[k] = Tr*ck + Ti*sk;
        Si[k] = Ti*ck - Tr*sk;
        float nc = ck*c1 - sk*s1;
        sk = ck*s1 + sk*c1;
        ck = nc;
    }
    #pragma unroll
    for (int k=0;k<16;++k){
        #pragma unroll
        for (int off=32; off; off>>=1){
            Sr[k] += __shfl_xor(Sr[k], off, 64);
            Si[k] += __shfl_xor(Si[k], off, 64);
        }
    }
    __shared__ float red[4][32];
    int wv = threadIdx.x >> 6, ln = threadIdx.x & 63;
    if (ln == 0){
        #pragma unroll
        for (int k=0;k<16;++k){ red[wv][2*k] = Sr[k]; red[wv][2*k+1] = Si[k]; }
    }
    __syncthreads();
    if (threadIdx.x < 32){
        float v = red[0][threadIdx.x]+red[1][threadIdx.x]+red[2][threadIdx.x]+red[3][threadIdx.x];
        S[bi*32 + threadIdx.x] = v * (1.0f/256.0f);
    }
}

// A[b,j,km] = sum_i S[b,i,k] * (wr + i wi)[i,j,km]
__global__ __launch_bounds__(256) void k_mixA(const float* __restrict__ S, const float* __restrict__ wr,
                                              const float* __restrict__ wi, float* __restrict__ A){
    int j = blockIdx.x >> 3, b = blockIdx.x & 7;
    __shared__ float sS[2048];
    for (int t=threadIdx.x; t<2048; t+=256) sS[t] = S[b*2048 + t];
    __syncthreads();
    int km = threadIdx.x, k = km >> 4;
    float ar = 0.f, ai = 0.f;
    const float* wrp = wr + j*256 + km;
    const float* wip = wi + j*256 + km;
    #pragma unroll 4
    for (int i=0;i<64;++i){
        float wrv = wrp[i*16384];
        float wiv = wip[i*16384];
        float2 sv = ((const float2*)sS)[i*16 + k];
        ar += sv.x*wrv - sv.y*wiv;
        ai += sv.x*wiv + sv.y*wrv;
    }
    ((float2*)A)[(b*64 + j)*256 + km] = make_float2(ar, ai);
}

// c = sum_j pw[o,j]*A[b,j,km]; Parseval stats; CS = c * inv_sigma * alpha(m) / 256
__global__ __launch_bounds__(256) void k_mixB(const float* __restrict__ A, const float* __restrict__ pw,
                                              float* __restrict__ CS){
    int b = blockIdx.x >> 6, o = blockIdx.x & 63;
    int km = threadIdx.x, m = km & 15;
    const float2* Ap = (const float2*)A + b*64*256 + km;
    const float* pwp = pw + o*64;
    float cr=0.f, ci=0.f;
    #pragma unroll 4
    for (int j=0;j<64;++j){
        float p = pwp[j];
        float2 a = Ap[j*256];
        cr = fmaf(p, a.x, cr);
        ci = fmaf(p, a.y, ci);
    }
    float aw = (m==0)? 1.f : 4.f;          // alpha(m)^2
    float s = (km==0)? 0.f : aw*(cr*cr + ci*ci);
    #pragma unroll
    for (int off=32; off; off>>=1) s += __shfl_xor(s, off, 64);
    __shared__ float rsum[4];
    __shared__ float sinv;
    if ((threadIdx.x & 63) == 0) rsum[threadIdx.x>>6] = s;
    __syncthreads();
    if (threadIdx.x == 0){
        float var = (rsum[0]+rsum[1]+rsum[2]+rsum[3]) * (1.0f/131072.0f); // /(2*H*W)
        sinv = rsqrtf(var + 1e-5f);
    }
    __syncthreads();
    float alpha = (m==0)? 1.f : 2.f;
    float sc = sinv * alpha * (1.0f/256.0f);
    if (km == 0) cr = 0.f;                 // remove mean (DC real part)
    ((float2*)CS)[blockIdx.x*256 + km] = make_float2(cr*sc, ci*sc);
}

// x += gelu(irfft-ish synth); LDS-shared V; optional T-emit.
template<bool EMIT_T>
__global__ __launch_bounds__(256) void k_synth(const float* __restrict__ CS, float* __restrict__ x,
                                               const float* __restrict__ GH, float* __restrict__ T){
    int bo = blockIdx.x >> 2, wt = blockIdx.x & 3;
    int lane = threadIdx.x & 63, wv = threadIdx.x >> 6;
    int w = wt*64 + lane;
    __shared__ float sGH[512];
    __shared__ float2 sV[16][64];
    if (EMIT_T){
        sGH[threadIdx.x] = GH[threadIdx.x];
        sGH[256+threadIdx.x] = GH[256+threadIdx.x];
    }
    const float2* cs = (const float2*)CS + bo*256;
    {   // phase A: thread computes V[k] for k in [4*wv, 4*wv+4)
        float Vr[4] = {0.f,0.f,0.f,0.f}, Vi[4] = {0.f,0.f,0.f,0.f};
        float stepc, steps; sincosf((float)w*TH_, &steps, &stepc);
        float pc = 1.f, ps = 0.f;          // e^{+i m th w}
        for (int m=0;m<16;++m){
            #pragma unroll
            for (int kk=0;kk<4;++kk){
                float2 a = cs[(wv*4+kk)*16 + m];
                Vr[kk] += a.x*pc - a.y*ps;
                Vi[kk] += a.x*ps + a.y*pc;
            }
            float nc = pc*stepc - ps*steps;
            ps = pc*steps + ps*stepc;
            pc = nc;
        }
        #pragma unroll
        for (int kk=0;kk<4;++kk) sV[wv*4+kk][lane] = make_float2(Vr[kk], Vi[kk]);
    }
    __syncthreads();
    int h0 = wv*16;
    float rc[16], rs[16], qr[16], qi[16];
    #pragma unroll
    for (int k=0;k<16;++k){
        float2 v = sV[k][lane];
        sincosf((float)k*TH_, &rs[k], &rc[k]);
        float c0, s0; sincosf((float)(k*h0)*TH_, &s0, &c0);
        qr[k] = v.x*c0 - v.y*s0;       // q = V * e^{+i th k h0}
        qi[k] = v.x*s0 + v.y*c0;
    }
    float* xp = x + ((size_t)bo << 16);
    float Tr = 0.f, Ti = 0.f;
    for (int i=0;i<16;++i){
        float y0=0.f,y1=0.f,y2=0.f,y3=0.f;
        #pragma unroll
        for (int k=0;k<16;++k){
            float re = qr[k], im = qi[k];
            y0 += re;                                   // h
            if ((k&3)==0)      { y1 += re; y2 += re; y3 += re; }   // *i^k, *(-1)^k, *(-i)^k
            else if ((k&3)==1) { y1 -= im; y2 -= re; y3 += im; }
            else if ((k&3)==2) { y1 -= re; y2 += re; y3 -= re; }
            else               { y1 += im; y2 -= re; y3 -= im; }
        }
        #pragma unroll
        for (int k=1;k<16;++k){
            float nr = qr[k]*rc[k] - qi[k]*rs[k];
            qi[k]    = qr[k]*rs[k] + qi[k]*rc[k];
            qr[k] = nr;
        }
        int p0 = (h0+i)*256 + w;
        float x0 = xp[p0], x1 = xp[p0+16384], x2 = xp[p0+32768], x3 = xp[p0+49152];
        float n0 = gelu_f(y0) + x0;
        float n1 = gelu_f(y1) + x1;
        float n2 = gelu_f(y2) + x2;
        float n3 = gelu_f(y3) + x3;
        xp[p0]       = n0;
        xp[p0+16384] = n1;
        xp[p0+32768] = n2;
        xp[p0+49152] = n3;
        if (EMIT_T){
            int h = h0+i;
            Tr = fmaf(sGH[2*h],     n0, Tr);  Ti = fmaf(sGH[2*h+1],     n0, Ti);
            Tr = fmaf(sGH[2*h+128], n1, Tr);  Ti = fmaf(sGH[2*h+129],   n1, Ti);
            Tr = fmaf(sGH[2*h+256], n2, Tr);  Ti = fmaf(sGH[2*h+257],   n2, Ti);
            Tr = fmaf(sGH[2*h+384], n3, Tr);  Ti = fmaf(sGH[2*h+385],   n3, Ti);
        }
    }
    if (EMIT_T){
        __shared__ float2 tpart[4][64];
        tpart[wv][lane] = make_float2(Tr, Ti);
        __syncthreads();
        if (wv == 0){
            float2 a = tpart[0][lane], b2 = tpart[1][lane];
            float2 c = tpart[2][lane], d = tpart[3][lane];
            ((float2*)T)[bo*256 + w] = make_float2(a.x+b2.x+c.x+d.x, a.y+b2.y+c.y+d.y);
        }
    }
}

// MFMA heads; Wf staged via LDS; mt=2 (32 px/wave). ph=1 writes final P outputs directly.
// NOTE (R10/R11 post-mortem): replacing the LDS staging with direct global bf16x8 reads
// + splitting the 6-MFMA chain into two accumulators produced absmax 3e36 twice —
// reverted to this proven version; do not retry without isolation.
__global__ __launch_bounds__(256) void k_heads(const float* __restrict__ x,
        const float* __restrict__ Wf, const float* __restrict__ st,
        const float* __restrict__ fb1, const float* __restrict__ fw2, const float* __restrict__ fb2,
        const float* __restrict__ qb1, const float* __restrict__ qw2, const float* __restrict__ qb2,
        float* __restrict__ J, float* __restrict__ outp){
    __shared__ bf16x8 sWf[2048];       // 32 KB: full split-bf16 W1 fragment table
    for (int t = threadIdx.x; t < 2048; t += 256)
        sWf[t] = ((const bf16x8*)Wf)[t];
    __syncthreads();

    int wv = threadIdx.x >> 6, lane = threadIdx.x & 63;
    int l15 = lane & 15, lg = lane >> 4;
    int px0 = blockIdx.x*128 + wv*32;     // 32 px per wave
    int b = px0 >> 16;
    int hwbase = px0 & (HW-1);
    const float* xb = x + (size_t)b*64*HW;

    // A fragments: 2 M-tiles x 2 k-steps, hi/lo bf16 via cvt_pk
    bf16x8 Ahi[2][2], Alo[2][2];
    #pragma unroll
    for (int mt=0; mt<2; ++mt){
        int px = hwbase + mt*16 + l15;
        #pragma unroll
        for (int ks=0; ks<2; ++ks){
            float f[8];
            #pragma unroll
            for (int j=0; j<8; ++j)
                f[j] = xb[(size_t)((ks*32 + lg*8 + j))*HW + px];
            split8(f, Ahi[mt][ks], Alo[mt][ks]);
        }
    }

    #pragma unroll
    for (int ph=0; ph<2; ++ph){
        const float* b1p = ph ? qb1 : fb1;
        const float* w2p = ph ? qw2 : fw2;
        const float* b2p = ph ? qb2 : fb2;

        float p0[8], p1[8];
        #pragma unroll
        for (int t=0;t<8;++t){ p0[t]=0.f; p1[t]=0.f; }

        for (int n=0; n<4; ++n){
            int oc = n*16 + l15;
            float bias = b1p[oc];
            float w2a = w2p[oc], w2b = w2p[64+oc];
            int base = ((ph*4+n)*2)*64 + lane;
            bf16x8 Bhi0 = sWf[base];
            bf16x8 Bhi1 = sWf[base + 64];
            bf16x8 Blo0 = sWf[1024 + base];
            bf16x8 Blo1 = sWf[1024 + base + 64];
            #pragma unroll
            for (int mt=0; mt<2; ++mt){
                f32x4 d = {0.f,0.f,0.f,0.f};
                d = __builtin_amdgcn_mfma_f32_16x16x32_bf16(Ahi[mt][0], Bhi0, d, 0,0,0);
                d = __builtin_amdgcn_mfma_f32_16x16x32_bf16(Ahi[mt][0], Blo0, d, 0,0,0);
                d = __builtin_amdgcn_mfma_f32_16x16x32_bf16(Alo[mt][0], Bhi0, d, 0,0,0);
                d = __builtin_amdgcn_mfma_f32_16x16x32_bf16(Ahi[mt][1], Bhi1, d, 0,0,0);
                d = __builtin_amdgcn_mfma_f32_16x16x32_bf16(Ahi[mt][1], Blo1, d, 0,0,0);
                d = __builtin_amdgcn_mfma_f32_16x16x32_bf16(Alo[mt][1], Bhi1, d, 0,0,0);
                #pragma unroll
                for (int r=0;r<4;++r){
                    float g = gelu_f(d[r] + bias);
                    p0[mt*4+r] = fmaf(w2a, g, p0[mt*4+r]);
                    p1[mt*4+r] = fmaf(w2b, g, p1[mt*4+r]);
                }
            }
        }
        #pragma unroll
        for (int t=0;t<8;++t){
            #pragma unroll
            for (int off=1; off<16; off<<=1){
                p0[t] += __shfl_xor(p0[t], off, 64);
                p1[t] += __shfl_xor(p1[t], off, 64);
            }
        }
        float bo0 = b2p[0], bo1 = b2p[1];
        if (ph == 0){
            if (l15 == 0){
                float* plane = J + ((size_t)(b*2 + 0))*HW;
                #pragma unroll
                for (int mt=0; mt<2; ++mt){
                    int px = hwbase + mt*16 + lg*4;
                    float4 v; v.x=p0[mt*4+0]+bo0; v.y=p0[mt*4+1]+bo0; v.z=p0[mt*4+2]+bo0; v.w=p0[mt*4+3]+bo0;
                    *(float4*)(plane + px) = v;
                }
            } else if (l15 == 1){
                float* plane = J + ((size_t)(b*2 + 1))*HW;
                #pragma unroll
                for (int mt=0; mt<2; ++mt){
                    int px = hwbase + mt*16 + lg*4;
                    float4 v; v.x=p1[mt*4+0]+bo1; v.y=p1[mt*4+1]+bo1; v.z=p1[mt*4+2]+bo1; v.w=p1[mt*4+3]+bo1;
                    *(float4*)(plane + px) = v;
                }
            }
        } else {
            if (l15 < 2){
                const float* pv = (l15==0)? p0 : p1;
                float bN = (l15==0)? bo0 : bo1;
                const float* plane_st  = st   + ((size_t)(b*3+1+l15))*HW;
                float* plane_pred      = outp + ((size_t)(b*3+1+l15))*HW;
                float* plane_dt        = outp + 1572864 + ((size_t)(b*3+1+l15))*HW;
                #pragma unroll
                for (int mt=0; mt<2; ++mt){
                    int px = hwbase + mt*16 + lg*4;
                    float4 sv = *(const float4*)(plane_st + px);
                    float4 dt, pd;
                    dt.x = pv[mt*4+0]+bN; dt.y = pv[mt*4+1]+bN;
                    dt.z = pv[mt*4+2]+bN; dt.w = pv[mt*4+3]+bN;
                    pd.x = fmaf(0.05f, dt.x, sv.x); pd.y = fmaf(0.05f, dt.y, sv.y);
                    pd.z = fmaf(0.05f, dt.z, sv.z); pd.w = fmaf(0.05f, dt.w, sv.w);
                    *(float4*)(plane_pred + px) = pd;
                    *(float4*)(plane_dt + px)   = dt;
                }
            }
        }
    }
}

// Divergence via real circular convolution (FFT-free; operator-identical to irfft2(i k rfft2)).
// k_convH: Dx[b,h,w] = sum_h' K[(h-h')&255]*Jx[b,h',w]; r[b,w] = sum_h (-1)^h Jx[b,h,w]
__global__ __launch_bounds__(256) void k_convH(const float* __restrict__ J, const float* __restrict__ KQ,
                                               float* __restrict__ Dx, float* __restrict__ r){
    int b = blockIdx.x >> 5, wt = blockIdx.x & 31;   // 8-wide w tiles
    int w0 = wt*8;
    __shared__ float tile[256][12];                  // pad 12 -> spread banks
    __shared__ float sK[256];
    int t = threadIdx.x;
    sK[t] = KQ[t];
    {
        const float* rp = J + (size_t)(b*2)*HW + t*256 + w0;
        float4 a = *(const float4*)rp;
        float4 bb = *(const float4*)(rp+4);
        tile[t][0]=a.x;  tile[t][1]=a.y;  tile[t][2]=a.z;  tile[t][3]=a.w;
        tile[t][4]=bb.x; tile[t][5]=bb.y; tile[t][6]=bb.z; tile[t][7]=bb.w;
    }
    __syncthreads();
    if (t < 8){
        float acc = 0.f;
        for (int h=0; h<256; ++h) acc += (h & 1)? -tile[h][t] : tile[h][t];
        r[b*256 + w0 + t] = acc;
    }
    float o[8] = {0.f,0.f,0.f,0.f,0.f,0.f,0.f,0.f};
    for (int hp=0; hp<256; ++hp){
        float k = sK[(t - hp) & 255];
        float4 ra = *(const float4*)&tile[hp][0];   // broadcast reads
        float4 rb = *(const float4*)&tile[hp][4];
        o[0]=fmaf(k, ra.x, o[0]); o[1]=fmaf(k, ra.y, o[1]);
        o[2]=fmaf(k, ra.z, o[2]); o[3]=fmaf(k, ra.w, o[3]);
        o[4]=fmaf(k, rb.x, o[4]); o[5]=fmaf(k, rb.y, o[5]);
        o[6]=fmaf(k, rb.z, o[6]); o[7]=fmaf(k, rb.w, o[7]);
    }
    float* dp = Dx + (size_t)b*HW + t*256 + w0;
    float4 v0; v0.x=o[0]; v0.y=o[1]; v0.z=o[2]; v0.w=o[3];
    float4 v1; v1.x=o[4]; v1.y=o[5]; v1.z=o[6]; v1.w=o[7];
    *(float4*)dp = v0;
    *(float4*)(dp+4) = v1;
}

// k_convW: dt_rho = -(Dx + conv_w(K,Jy) + 0.5*(-1)^h * conv_w(Q,r)); write rho outputs.
__global__ __launch_bounds__(256) void k_convW(const float* __restrict__ J, const float* __restrict__ KQ,
                                               const float* __restrict__ Dx, const float* __restrict__ r,
                                               const float* __restrict__ st, float* __restrict__ outp){
    int b = blockIdx.x >> 5, ht = blockIdx.x & 31;   // 8-row h tiles
    int h0 = ht*8;
    __shared__ float rows[8][256];
    __shared__ float sr[256], sK[256], sQ[256];
    int t = threadIdx.x;
    sK[t] = KQ[t];
    sQ[t] = KQ[256+t];
    sr[t] = r[b*256 + t];
    const float* jy = J + (size_t)(b*2+1)*HW;
    #pragma unroll
    for (int i=0;i<8;++i) rows[i][t] = jy[(h0+i)*256 + t];
    __syncthreads();
    float P = 0.f;
    float cv[8] = {0.f,0.f,0.f,0.f,0.f,0.f,0.f,0.f};
    for (int wp=0; wp<256; ++wp){
        int d = (t - wp) & 255;
        float kk = sK[d];
        P = fmaf(sQ[d], sr[wp], P);
        #pragma unroll
        for (int i=0;i<8;++i) cv[i] = fmaf(kk, rows[i][wp], cv[i]);
    }
    const float* s0p = st + (size_t)(b*3)*HW;
    const float* dxp = Dx + (size_t)b*HW;
    float* o_rho = outp + (size_t)(b*3)*HW;
    float* o_dt  = outp + 1572864 + (size_t)(b*3)*HW;
    #pragma unroll
    for (int i=0;i<8;++i){
        int h = h0 + i;
        int idx = h*256 + t;
        float corr = ((h & 1)? -0.5f : 0.5f) * P;
        float rho = -(dxp[idx] + cv[i] + corr);
        float tt = 10.f*fmaf(0.05f, rho, s0p[idx]);
        float sp = fmaxf(tt, 0.f) + log1pf(expf(-fabsf(tt)));
        o_rho[idx] = 0.1f*sp;
        o_dt[idx]  = rho;
    }
}

extern "C" void kernel_launch(void* const* d_in, const int* in_sizes, int n_in,
                              void* d_out, int out_size, void* d_ws, size_t ws_size,
                              hipStream_t stream){
    const float* state = (const float*)d_in[0];
    const float* lw  = (const float*)d_in[1];
    const float* lb  = (const float*)d_in[2];
    const float* swr = (const float*)d_in[3];
    const float* swi = (const float*)d_in[4];
    const float* pww = (const float*)d_in[5];
    // d_in[6] = pw_b : cancels exactly in InstanceNorm, unused
    const float* fw1 = (const float*)d_in[7];
    const float* fb1 = (const float*)d_in[8];
    const float* fw2 = (const float*)d_in[9];
    const float* fb2 = (const float*)d_in[10];
    const float* qw1 = (const float*)d_in[11];
    const float* qb1 = (const float*)d_in[12];
    const float* qw2 = (const float*)d_in[13];
    const float* qb2 = (const float*)d_in[14];
    float* outp = (float*)d_out;
    float* ws = (float*)d_ws;

    float* x   = ws;                    // 33,554,432 f32
    float* S   = x   + 33554432;        // 16,384
    float* A   = S   + 16384;           // 262,144
    float* CS  = A   + 262144;          // 262,144
    float* J   = CS  + 262144;          // 1,048,576 (Jx/Jy planes per b)
    float* Dx  = J   + 1048576;         // 524,288
    float* rr  = Dx  + 524288;          // 2,048
    float* GH  = rr  + 2048;            // 512
    float* KQ  = GH  + 512;             // 512
    float* Wf  = KQ  + 512;             // 8,192 f32 slots (2048 bf16x8 frags)
    float* T   = J;                     // alias: T dead before k_heads writes J

    hipLaunchKernelGGL(k_init,  dim3(5), dim3(256), 0, stream, fw1, qw1, Wf, GH, KQ);
    hipLaunchKernelGGL(k_lift2, dim3(512), dim3(1024), 0, stream, state, lw, lb, GH, x, T);
    for (int l=0; l<4; ++l){
        hipLaunchKernelGGL(k_analysisT, dim3(512), dim3(256), 0, stream, T, S);
        hipLaunchKernelGGL(k_mixA, dim3(512), dim3(256), 0, stream, S,
                           swr + (size_t)l*1048576, swi + (size_t)l*1048576, A);
        hipLaunchKernelGGL(k_mixB, dim3(512), dim3(256), 0, stream, A, pww + l*4096, CS);
        if (l < 3)
            hipLaunchKernelGGL((k_synth<true>),  dim3(2048), dim3(256), 0, stream, CS, x, GH, T);
        else
            hipLaunchKernelGGL((k_synth<false>), dim3(2048), dim3(256), 0, stream, CS, x, GH, T);
    }
    hipLaunchKernelGGL(k_heads, dim3(4096), dim3(256), 0, stream, x,
                       Wf, state, fb1, fw2, fb2, qb1, qw2, qb2, J, outp);
    hipLaunchKernelGGL(k_convH, dim3(256), dim3(256), 0, stream, J, KQ, Dx, rr);
    hipLaunchKernelGGL(k_convW, dim3(256), dim3(256), 0, stream, J, KQ, Dx, rr, state, outp);
}

// Round 13
// 475.959 us; speedup vs baseline: 1.5120x; 1.0124x over previous
//
#include <hip/hip_runtime.h>
#include <math.h>

#define HW 65536
#define TH_ 0.024543692606170259f  // 2*pi/256

typedef __attribute__((ext_vector_type(8))) short bf16x8;
typedef __attribute__((ext_vector_type(4))) float f32x4;

// Fast gelu: Abramowitz-Stegun 7.1.26 erf, |abs err| ~3e-7.
__device__ __forceinline__ float gelu_f(float v){
    float u = fabsf(v)*0.7071067811865476f;
    float t = __builtin_amdgcn_rcpf(fmaf(0.3275911f, u, 1.0f));
    float p = t*fmaf(t, fmaf(t, fmaf(t, fmaf(t, 1.061405429f, -1.453152027f),
                     1.421413741f), -0.284496736f), 0.254829592f);
    float e = __expf(-u*u);
    float erfu = fmaf(-p, e, 1.0f);
    float er = copysignf(erfu, v);
    return 0.5f*v*(1.0f+er);
}

__device__ __forceinline__ short f2bf(float f){
    union { float f; unsigned u; } v; v.f = f;
    unsigned r = (v.u + 0x7FFF + ((v.u >> 16) & 1)) >> 16;   // RNE
    return (short)r;
}
__device__ __forceinline__ float bf2f(short s){
    union { float f; unsigned u; } v; v.u = ((unsigned)(unsigned short)s) << 16;
    return v.f;
}

// v_cvt_pk_bf16_f32: D.lo = bf16(S0), D.hi = bf16(S1)
__device__ __forceinline__ unsigned cvt_pk_bf16(float lo, float hi){
    unsigned r;
    asm("v_cvt_pk_bf16_f32 %0, %1, %2" : "=v"(r) : "v"(lo), "v"(hi));
    return r;
}

union U8 { bf16x8 v; unsigned u[4]; };

// split 8 floats -> hi/lo bf16x8 using packed converts
__device__ __forceinline__ void split8(const float* f, bf16x8& H, bf16x8& L){
    U8 h, l;
    #pragma unroll
    for (int p=0;p<4;++p){
        float a = f[2*p], b = f[2*p+1];
        unsigned hp = cvt_pk_bf16(a, b);
        union { unsigned u; float fl; } ua, ub;
        ua.u = hp << 16; ub.u = hp & 0xffff0000u;
        h.u[p] = hp;
        l.u[p] = cvt_pk_bf16(a - ua.fl, b - ub.fl);
    }
    H = h.v; L = l.v;
}

// Per-wave S-partial accumulation: lanes hold T(w) for 64 consecutive w;
// compute Sr/Si[k] = Re/Im(T e^{-i k th w})/256, reduce over the wave, atomicAdd 32 floats.
__device__ __forceinline__ void s_partial_atomic(float TrT, float TiT, int w, int lane,
                                                 float* __restrict__ Sdst){
    float c1, s1; sincosf((float)w * TH_, &s1, &c1);
    float Sr[16], Si[16];
    float ck = 1.f, sk = 0.f;
    #pragma unroll
    for (int k=0;k<16;++k){
        Sr[k] = (TrT*ck + TiT*sk) * (1.0f/256.0f);
        Si[k] = (TiT*ck - TrT*sk) * (1.0f/256.0f);
        float nc = ck*c1 - sk*s1;
        sk = ck*s1 + sk*c1;
        ck = nc;
    }
    #pragma unroll
    for (int k=0;k<16;++k){
        #pragma unroll
        for (int off=32; off; off>>=1){
            Sr[k] += __shfl_xor(Sr[k], off, 64);
            Si[k] += __shfl_xor(Si[k], off, 64);
        }
    }
    if (lane < 32){
        float val = (lane & 1) ? Si[lane>>1] : Sr[lane>>1];
        atomicAdd(Sdst + lane, val);
    }
}

// Merged init: blocks 0-3 = prepW fragments, block 4 = GH/KQ tables.
__global__ __launch_bounds__(256) void k_init(const float* __restrict__ fw1, const float* __restrict__ qw1,
                                              float* __restrict__ Wf, float* __restrict__ GH,
                                              float* __restrict__ KQ){
    if (blockIdx.x == 4){
        int h = threadIdx.x;
        double gr = 0.0, gi = 0.0;
        for (int ky=0; ky<16; ++ky){
            double a = -2.0*3.14159265358979323846*(double)(ky*h)/256.0;
            gr += cos(a); gi += sin(a);
        }
        GH[2*h] = (float)gr; GH[2*h+1] = (float)gi;
        double kk = 0.0, qq = 0.0;
        for (int k=1; k<128; ++k){
            double s = sin(2.0*3.14159265358979323846*(double)(k*h)/256.0);
            kk += (double)k * s;
            qq += s;
        }
        KQ[h]     = (float)(-kk/128.0);
        KQ[256+h] = (float)( qq/128.0);
        return;
    }
    int t = blockIdx.x*256 + threadIdx.x;       // 1024 total
    int lane = t & 63, ks = (t>>6)&1, n = (t>>7)&3, ph = (t>>9)&1;
    int l15 = lane & 15, lg = lane >> 4;
    const float* w1p = ph ? qw1 : fw1;
    int oc = n*16 + l15;
    U8 h, l;
    #pragma unroll
    for (int p=0;p<4;++p){
        float a = w1p[oc*64 + ks*32 + lg*8 + 2*p];
        float b = w1p[oc*64 + ks*32 + lg*8 + 2*p+1];
        short ha = f2bf(a), hb = f2bf(b);
        h.u[p] = ((unsigned)(unsigned short)ha) | (((unsigned)(unsigned short)hb)<<16);
        short la = f2bf(a - bf2f(ha)), lb = f2bf(b - bf2f(hb));
        l.u[p] = ((unsigned)(unsigned short)la) | (((unsigned)(unsigned short)lb)<<16);
    }
    int idx = ((ph*4+n)*2+ks)*64 + lane;
    ((bf16x8*)Wf)[idx] = h.v;
    ((bf16x8*)Wf)[1024 + idx] = l.v;
}

// Fused lift + layer-0 S-projection; 1024 threads: (w, hq) with hq = 64-row quarter.
// S partials accumulated directly via atomics (analysisT kernel eliminated).
__global__ __launch_bounds__(1024) void k_lift2(const float* __restrict__ st, const float* __restrict__ lw,
                                                const float* __restrict__ lb, const float* __restrict__ GH,
                                                float* __restrict__ x, float* __restrict__ Sout){
    int b = blockIdx.x >> 6, c = blockIdx.x & 63;
    int t = threadIdx.x;
    int w = t & 255, hq = t >> 8;
    __shared__ float sGH[512];
    __shared__ float2 tp[4][256];
    if (t < 512) sGH[t] = GH[t];
    __syncthreads();
    float l0 = lw[c*3], l1 = lw[c*3+1], l2 = lw[c*3+2], lbc = lb[c];
    const float* s0p = st + (size_t)(b*3)*HW;
    float* xp = x + (size_t)blockIdx.x*HW;
    float Tr = 0.f, Ti = 0.f;
    #pragma unroll 4
    for (int i=0; i<64; ++i){
        int h = hq*64 + i;
        int idx = h*256 + w;
        float v = fmaf(l0, s0p[idx], fmaf(l1, s0p[HW+idx], fmaf(l2, s0p[2*HW+idx], lbc)));
        v = gelu_f(v);
        xp[idx] = v;
        Tr = fmaf(sGH[2*h],   v, Tr);
        Ti = fmaf(sGH[2*h+1], v, Ti);
    }
    tp[hq][w] = make_float2(Tr, Ti);
    __syncthreads();
    if (hq == 0){   // threads 0..255 = waves 0..3, full waves, w == t
        float2 a = tp[0][w], b2 = tp[1][w], cc = tp[2][w], d = tp[3][w];
        float TrT = a.x+b2.x+cc.x+d.x, TiT = a.y+b2.y+cc.y+d.y;
        s_partial_atomic(TrT, TiT, w, t & 63, Sout + blockIdx.x*32);
    }
}

// A[b,j,km] = sum_i S[b,i,k] * (wr + i wi)[i,j,km]
__global__ __launch_bounds__(256) void k_mixA(const float* __restrict__ S, const float* __restrict__ wr,
                                              const float* __restrict__ wi, float* __restrict__ A){
    int j = blockIdx.x >> 3, b = blockIdx.x & 7;
    __shared__ float sS[2048];
    for (int t=threadIdx.x; t<2048; t+=256) sS[t] = S[b*2048 + t];
    __syncthreads();
    int km = threadIdx.x, k = km >> 4;
    float ar = 0.f, ai = 0.f;
    const float* wrp = wr + j*256 + km;
    const float* wip = wi + j*256 + km;
    #pragma unroll 4
    for (int i=0;i<64;++i){
        float wrv = wrp[i*16384];
        float wiv = wip[i*16384];
        float2 sv = ((const float2*)sS)[i*16 + k];
        ar += sv.x*wrv - sv.y*wiv;
        ai += sv.x*wiv + sv.y*wrv;
    }
    ((float2*)A)[(b*64 + j)*256 + km] = make_float2(ar, ai);
}

// c = sum_j pw[o,j]*A[b,j,km]; Parseval stats; CS = c * inv_sigma * alpha(m) / 256
__global__ __launch_bounds__(256) void k_mixB(const float* __restrict__ A, const float* __restrict__ pw,
                                              float* __restrict__ CS){
    int b = blockIdx.x >> 6, o = blockIdx.x & 63;
    int km = threadIdx.x, m = km & 15;
    const float2* Ap = (const float2*)A + b*64*256 + km;
    const float* pwp = pw + o*64;
    float cr=0.f, ci=0.f;
    #pragma unroll 4
    for (int j=0;j<64;++j){
        float p = pwp[j];
        float2 a = Ap[j*256];
        cr = fmaf(p, a.x, cr);
        ci = fmaf(p, a.y, ci);
    }
    float aw = (m==0)? 1.f : 4.f;          // alpha(m)^2
    float s = (km==0)? 0.f : aw*(cr*cr + ci*ci);
    #pragma unroll
    for (int off=32; off; off>>=1) s += __shfl_xor(s, off, 64);
    __shared__ float rsum[4];
    __shared__ float sinv;
    if ((threadIdx.x & 63) == 0) rsum[threadIdx.x>>6] = s;
    __syncthreads();
    if (threadIdx.x == 0){
        float var = (rsum[0]+rsum[1]+rsum[2]+rsum[3]) * (1.0f/131072.0f); // /(2*H*W)
        sinv = rsqrtf(var + 1e-5f);
    }
    __syncthreads();
    float alpha = (m==0)? 1.f : 2.f;
    float sc = sinv * alpha * (1.0f/256.0f);
    if (km == 0) cr = 0.f;                 // remove mean (DC real part)
    ((float2*)CS)[blockIdx.x*256 + km] = make_float2(cr*sc, ci*sc);
}

// x += gelu(irfft-ish synth); LDS-shared V; EMIT_S: accumulate next layer's S via atomics.
template<bool EMIT_S>
__global__ __launch_bounds__(256) void k_synth(const float* __restrict__ CS, float* __restrict__ x,
                                               const float* __restrict__ GH, float* __restrict__ Sout){
    int bo = blockIdx.x >> 2, wt = blockIdx.x & 3;
    int lane = threadIdx.x & 63, wv = threadIdx.x >> 6;
    int w = wt*64 + lane;
    __shared__ float sGH[512];
    __shared__ float2 sV[16][64];
    if (EMIT_S){
        sGH[threadIdx.x] = GH[threadIdx.x];
        sGH[256+threadIdx.x] = GH[256+threadIdx.x];
    }
    const float2* cs = (const float2*)CS + bo*256;
    {   // phase A: thread computes V[k] for k in [4*wv, 4*wv+4)
        float Vr[4] = {0.f,0.f,0.f,0.f}, Vi[4] = {0.f,0.f,0.f,0.f};
        float stepc, steps; sincosf((float)w*TH_, &steps, &stepc);
        float pc = 1.f, ps = 0.f;          // e^{+i m th w}
        for (int m=0;m<16;++m){
            #pragma unroll
            for (int kk=0;kk<4;++kk){
                float2 a = cs[(wv*4+kk)*16 + m];
                Vr[kk] += a.x*pc - a.y*ps;
                Vi[kk] += a.x*ps + a.y*pc;
            }
            float nc = pc*stepc - ps*steps;
            ps = pc*steps + ps*stepc;
            pc = nc;
        }
        #pragma unroll
        for (int kk=0;kk<4;++kk) sV[wv*4+kk][lane] = make_float2(Vr[kk], Vi[kk]);
    }
    __syncthreads();
    int h0 = wv*16;
    float rc[16], rs[16], qr[16], qi[16];
    #pragma unroll
    for (int k=0;k<16;++k){
        float2 v = sV[k][lane];
        sincosf((float)k*TH_, &rs[k], &rc[k]);
        float c0, s0; sincosf((float)(k*h0)*TH_, &s0, &c0);
        qr[k] = v.x*c0 - v.y*s0;       // q = V * e^{+i th k h0}
        qi[k] = v.x*s0 + v.y*c0;
    }
    float* xp = x + ((size_t)bo << 16);
    float Tr = 0.f, Ti = 0.f;
    for (int i=0;i<16;++i){
        float y0=0.f,y1=0.f,y2=0.f,y3=0.f;
        #pragma unroll
        for (int k=0;k<16;++k){
            float re = qr[k], im = qi[k];
            y0 += re;                                   // h
            if ((k&3)==0)      { y1 += re; y2 += re; y3 += re; }   // *i^k, *(-1)^k, *(-i)^k
            else if ((k&3)==1) { y1 -= im; y2 -= re; y3 += im; }
            else if ((k&3)==2) { y1 -= re; y2 += re; y3 -= re; }
            else               { y1 += im; y2 -= re; y3 -= im; }
        }
        #pragma unroll
        for (int k=1;k<16;++k){
            float nr = qr[k]*rc[k] - qi[k]*rs[k];
            qi[k]    = qr[k]*rs[k] + qi[k]*rc[k];
            qr[k] = nr;
        }
        int p0 = (h0+i)*256 + w;
        float x0 = xp[p0], x1 = xp[p0+16384], x2 = xp[p0+32768], x3 = xp[p0+49152];
        float n0 = gelu_f(y0) + x0;
        float n1 = gelu_f(y1) + x1;
        float n2 = gelu_f(y2) + x2;
        float n3 = gelu_f(y3) + x3;
        xp[p0]       = n0;
        xp[p0+16384] = n1;
        xp[p0+32768] = n2;
        xp[p0+49152] = n3;
        if (EMIT_S){
            int h = h0+i;
            Tr = fmaf(sGH[2*h],     n0, Tr);  Ti = fmaf(sGH[2*h+1],     n0, Ti);
            Tr = fmaf(sGH[2*h+128], n1, Tr);  Ti = fmaf(sGH[2*h+129],   n1, Ti);
            Tr = fmaf(sGH[2*h+256], n2, Tr);  Ti = fmaf(sGH[2*h+257],   n2, Ti);
            Tr = fmaf(sGH[2*h+384], n3, Tr);  Ti = fmaf(sGH[2*h+385],   n3, Ti);
        }
    }
    if (EMIT_S){
        __shared__ float2 tpart[4][64];
        tpart[wv][lane] = make_float2(Tr, Ti);
        __syncthreads();
        if (wv == 0){
            float2 a = tpart[0][lane], b2 = tpart[1][lane];
            float2 c = tpart[2][lane], d = tpart[3][lane];
            float TrT = a.x+b2.x+c.x+d.x, TiT = a.y+b2.y+c.y+d.y;
            s_partial_atomic(TrT, TiT, w, lane, Sout + bo*32);
        }
    }
}

// MFMA heads; Wf staged via LDS; mt=2 (32 px/wave). ph=1 writes final P outputs directly.
// NOTE (R10/R11 post-mortem): replacing the LDS staging with direct global bf16x8 reads
// + splitting the 6-MFMA chain into two accumulators produced absmax 3e36 twice —
// reverted to this proven version; do not retry without isolation.
__global__ __launch_bounds__(256) void k_heads(const float* __restrict__ x,
        const float* __restrict__ Wf, const float* __restrict__ st,
        const float* __restrict__ fb1, const float* __restrict__ fw2, const float* __restrict__ fb2,
        const float* __restrict__ qb1, const float* __restrict__ qw2, const float* __restrict__ qb2,
        float* __restrict__ J, float* __restrict__ outp){
    __shared__ bf16x8 sWf[2048];       // 32 KB: full split-bf16 W1 fragment table
    for (int t = threadIdx.x; t < 2048; t += 256)
        sWf[t] = ((const bf16x8*)Wf)[t];
    __syncthreads();

    int wv = threadIdx.x >> 6, lane = threadIdx.x & 63;
    int l15 = lane & 15, lg = lane >> 4;
    int px0 = blockIdx.x*128 + wv*32;     // 32 px per wave
    int b = px0 >> 16;
    int hwbase = px0 & (HW-1);
    const float* xb = x + (size_t)b*64*HW;

    // A fragments: 2 M-tiles x 2 k-steps, hi/lo bf16 via cvt_pk
    bf16x8 Ahi[2][2], Alo[2][2];
    #pragma unroll
    for (int mt=0; mt<2; ++mt){
        int px = hwbase + mt*16 + l15;
        #pragma unroll
        for (int ks=0; ks<2; ++ks){
            float f[8];
            #pragma unroll
            for (int j=0; j<8; ++j)
                f[j] = xb[(size_t)((ks*32 + lg*8 + j))*HW + px];
            split8(f, Ahi[mt][ks], Alo[mt][ks]);
        }
    }

    #pragma unroll
    for (int ph=0; ph<2; ++ph){
        const float* b1p = ph ? qb1 : fb1;
        const float* w2p = ph ? qw2 : fw2;
        const float* b2p = ph ? qb2 : fb2;

        float p0[8], p1[8];
        #pragma unroll
        for (int t=0;t<8;++t){ p0[t]=0.f; p1[t]=0.f; }

        for (int n=0; n<4; ++n){
            int oc = n*16 + l15;
            float bias = b1p[oc];
            float w2a = w2p[oc], w2b = w2p[64+oc];
            int base = ((ph*4+n)*2)*64 + lane;
            bf16x8 Bhi0 = sWf[base];
            bf16x8 Bhi1 = sWf[base + 64];
            bf16x8 Blo0 = sWf[1024 + base];
            bf16x8 Blo1 = sWf[1024 + base + 64];
            #pragma unroll
            for (int mt=0; mt<2; ++mt){
                f32x4 d = {0.f,0.f,0.f,0.f};
                d = __builtin_amdgcn_mfma_f32_16x16x32_bf16(Ahi[mt][0], Bhi0, d, 0,0,0);
                d = __builtin_amdgcn_mfma_f32_16x16x32_bf16(Ahi[mt][0], Blo0, d, 0,0,0);
                d = __builtin_amdgcn_mfma_f32_16x16x32_bf16(Alo[mt][0], Bhi0, d, 0,0,0);
                d = __builtin_amdgcn_mfma_f32_16x16x32_bf16(Ahi[mt][1], Bhi1, d, 0,0,0);
                d = __builtin_amdgcn_mfma_f32_16x16x32_bf16(Ahi[mt][1], Blo1, d, 0,0,0);
                d = __builtin_amdgcn_mfma_f32_16x16x32_bf16(Alo[mt][1], Bhi1, d, 0,0,0);
                #pragma unroll
                for (int r=0;r<4;++r){
                    float g = gelu_f(d[r] + bias);
                    p0[mt*4+r] = fmaf(w2a, g, p0[mt*4+r]);
                    p1[mt*4+r] = fmaf(w2b, g, p1[mt*4+r]);
                }
            }
        }
        #pragma unroll
        for (int t=0;t<8;++t){
            #pragma unroll
            for (int off=1; off<16; off<<=1){
                p0[t] += __shfl_xor(p0[t], off, 64);
                p1[t] += __shfl_xor(p1[t], off, 64);
            }
        }
        float bo0 = b2p[0], bo1 = b2p[1];
        if (ph == 0){
            if (l15 == 0){
                float* plane = J + ((size_t)(b*2 + 0))*HW;
                #pragma unroll
                for (int mt=0; mt<2; ++mt){
                    int px = hwbase + mt*16 + lg*4;
                    float4 v; v.x=p0[mt*4+0]+bo0; v.y=p0[mt*4+1]+bo0; v.z=p0[mt*4+2]+bo0; v.w=p0[mt*4+3]+bo0;
                    *(float4*)(plane + px) = v;
                }
            } else if (l15 == 1){
                float* plane = J + ((size_t)(b*2 + 1))*HW;
                #pragma unroll
                for (int mt=0; mt<2; ++mt){
                    int px = hwbase + mt*16 + lg*4;
                    float4 v; v.x=p1[mt*4+0]+bo1; v.y=p1[mt*4+1]+bo1; v.z=p1[mt*4+2]+bo1; v.w=p1[mt*4+3]+bo1;
                    *(float4*)(plane + px) = v;
                }
            }
        } else {
            if (l15 < 2){
                const float* pv = (l15==0)? p0 : p1;
                float bN = (l15==0)? bo0 : bo1;
                const float* plane_st  = st   + ((size_t)(b*3+1+l15))*HW;
                float* plane_pred      = outp + ((size_t)(b*3+1+l15))*HW;
                float* plane_dt        = outp + 1572864 + ((size_t)(b*3+1+l15))*HW;
                #pragma unroll
                for (int mt=0; mt<2; ++mt){
                    int px = hwbase + mt*16 + lg*4;
                    float4 sv = *(const float4*)(plane_st + px);
                    float4 dt, pd;
                    dt.x = pv[mt*4+0]+bN; dt.y = pv[mt*4+1]+bN;
                    dt.z = pv[mt*4+2]+bN; dt.w = pv[mt*4+3]+bN;
                    pd.x = fmaf(0.05f, dt.x, sv.x); pd.y = fmaf(0.05f, dt.y, sv.y);
                    pd.z = fmaf(0.05f, dt.z, sv.z); pd.w = fmaf(0.05f, dt.w, sv.w);
                    *(float4*)(plane_pred + px) = pd;
                    *(float4*)(plane_dt + px)   = dt;
                }
            }
        }
    }
}

// Divergence via real circular convolution (FFT-free; operator-identical to irfft2(i k rfft2)).
// k_convH: Dx[b,h,w] = sum_h' K[(h-h')&255]*Jx[b,h',w]; r[b,w] = sum_h (-1)^h Jx[b,h,w]
__global__ __launch_bounds__(256) void k_convH(const float* __restrict__ J, const float* __restrict__ KQ,
                                               float* __restrict__ Dx, float* __restrict__ r){
    int b = blockIdx.x >> 5, wt = blockIdx.x & 31;   // 8-wide w tiles
    int w0 = wt*8;
    __shared__ float tile[256][12];                  // pad 12 -> spread banks
    __shared__ float sK[256];
    int t = threadIdx.x;
    sK[t] = KQ[t];
    {
        const float* rp = J + (size_t)(b*2)*HW + t*256 + w0;
        float4 a = *(const float4*)rp;
        float4 bb = *(const float4*)(rp+4);
        tile[t][0]=a.x;  tile[t][1]=a.y;  tile[t][2]=a.z;  tile[t][3]=a.w;
        tile[t][4]=bb.x; tile[t][5]=bb.y; tile[t][6]=bb.z; tile[t][7]=bb.w;
    }
    __syncthreads();
    if (t < 8){
        float acc = 0.f;
        for (int h=0; h<256; ++h) acc += (h & 1)? -tile[h][t] : tile[h][t];
        r[b*256 + w0 + t] = acc;
    }
    float o[8] = {0.f,0.f,0.f,0.f,0.f,0.f,0.f,0.f};
    for (int hp=0; hp<256; ++hp){
        float k = sK[(t - hp) & 255];
        float4 ra = *(const float4*)&tile[hp][0];   // broadcast reads
        float4 rb = *(const float4*)&tile[hp][4];
        o[0]=fmaf(k, ra.x, o[0]); o[1]=fmaf(k, ra.y, o[1]);
        o[2]=fmaf(k, ra.z, o[2]); o[3]=fmaf(k, ra.w, o[3]);
        o[4]=fmaf(k, rb.x, o[4]); o[5]=fmaf(k, rb.y, o[5]);
        o[6]=fmaf(k, rb.z, o[6]); o[7]=fmaf(k, rb.w, o[7]);
    }
    float* dp = Dx + (size_t)b*HW + t*256 + w0;
    float4 v0; v0.x=o[0]; v0.y=o[1]; v0.z=o[2]; v0.w=o[3];
    float4 v1; v1.x=o[4]; v1.y=o[5]; v1.z=o[6]; v1.w=o[7];
    *(float4*)dp = v0;
    *(float4*)(dp+4) = v1;
}

// k_convW: dt_rho = -(Dx + conv_w(K,Jy) + 0.5*(-1)^h * conv_w(Q,r)); write rho outputs.
__global__ __launch_bounds__(256) void k_convW(const float* __restrict__ J, const float* __restrict__ KQ,
                                               const float* __restrict__ Dx, const float* __restrict__ r,
                                               const float* __restrict__ st, float* __restrict__ outp){
    int b = blockIdx.x >> 5, ht = blockIdx.x & 31;   // 8-row h tiles
    int h0 = ht*8;
    __shared__ float rows[8][256];
    __shared__ float sr[256], sK[256], sQ[256];
    int t = threadIdx.x;
    sK[t] = KQ[t];
    sQ[t] = KQ[256+t];
    sr[t] = r[b*256 + t];
    const float* jy = J + (size_t)(b*2+1)*HW;
    #pragma unroll
    for (int i=0;i<8;++i) rows[i][t] = jy[(h0+i)*256 + t];
    __syncthreads();
    float P = 0.f;
    float cv[8] = {0.f,0.f,0.f,0.f,0.f,0.f,0.f,0.f};
    for (int wp=0; wp<256; ++wp){
        int d = (t - wp) & 255;
        float kk = sK[d];
        P = fmaf(sQ[d], sr[wp], P);
        #pragma unroll
        for (int i=0;i<8;++i) cv[i] = fmaf(kk, rows[i][wp], cv[i]);
    }
    const float* s0p = st + (size_t)(b*3)*HW;
    const float* dxp = Dx + (size_t)b*HW;
    float* o_rho = outp + (size_t)(b*3)*HW;
    float* o_dt  = outp + 1572864 + (size_t)(b*3)*HW;
    #pragma unroll
    for (int i=0;i<8;++i){
        int h = h0 + i;
        int idx = h*256 + t;
        float corr = ((h & 1)? -0.5f : 0.5f) * P;
        float rho = -(dxp[idx] + cv[i] + corr);
        float tt = 10.f*fmaf(0.05f, rho, s0p[idx]);
        float sp = fmaxf(tt, 0.f) + log1pf(expf(-fabsf(tt)));
        o_rho[idx] = 0.1f*sp;
        o_dt[idx]  = rho;
    }
}

extern "C" void kernel_launch(void* const* d_in, const int* in_sizes, int n_in,
                              void* d_out, int out_size, void* d_ws, size_t ws_size,
                              hipStream_t stream){
    const float* state = (const float*)d_in[0];
    const float* lw  = (const float*)d_in[1];
    const float* lb  = (const float*)d_in[2];
    const float* swr = (const float*)d_in[3];
    const float* swi = (const float*)d_in[4];
    const float* pww = (const float*)d_in[5];
    // d_in[6] = pw_b : cancels exactly in InstanceNorm, unused
    const float* fw1 = (const float*)d_in[7];
    const float* fb1 = (const float*)d_in[8];
    const float* fw2 = (const float*)d_in[9];
    const float* fb2 = (const float*)d_in[10];
    const float* qw1 = (const float*)d_in[11];
    const float* qb1 = (const float*)d_in[12];
    const float* qw2 = (const float*)d_in[13];
    const float* qb2 = (const float*)d_in[14];
    float* outp = (float*)d_out;
    float* ws = (float*)d_ws;

    float* x   = ws;                    // 33,554,432 f32
    float* S   = x   + 33554432;        // 65,536 (4 per-layer S buffers, 16384 each)
    float* A   = S   + 65536;           // 262,144
    float* CS  = A   + 262144;          // 262,144
    float* J   = CS  + 262144;          // 1,048,576 (Jx/Jy planes per b)
    float* Dx  = J   + 1048576;         // 524,288
    float* rr  = Dx  + 524288;          // 2,048
    float* GH  = rr  + 2048;            // 512
    float* KQ  = GH  + 512;             // 512
    float* Wf  = KQ  + 512;             // 8,192 f32 slots (2048 bf16x8 frags)

    hipLaunchKernelGGL(k_init,  dim3(5), dim3(256), 0, stream, fw1, qw1, Wf, GH, KQ);
    hipMemsetAsync(S, 0, 65536*sizeof(float), stream);   // S accumulated via atomics
    hipLaunchKernelGGL(k_lift2, dim3(512), dim3(1024), 0, stream, state, lw, lb, GH, x, S);
    for (int l=0; l<4; ++l){
        float* Sl = S + l*16384;
        hipLaunchKernelGGL(k_mixA, dim3(512), dim3(256), 0, stream, Sl,
                           swr + (size_t)l*1048576, swi + (size_t)l*1048576, A);
        hipLaunchKernelGGL(k_mixB, dim3(512), dim3(256), 0, stream, A, pww + l*4096, CS);
        if (l < 3)
            hipLaunchKernelGGL((k_synth<true>),  dim3(2048), dim3(256), 0, stream, CS, x, GH, S + (l+1)*16384);
        else
            hipLaunchKernelGGL((k_synth<false>), dim3(2048), dim3(256), 0, stream, CS, x, GH, S);
    }
    hipLaunchKernelGGL(k_heads, dim3(4096), dim3(256), 0, stream, x,
                       Wf, state, fb1, fw2, fb2, qb1, qw2, qb2, J, outp);
    hipLaunchKernelGGL(k_convH, dim3(256), dim3(256), 0, stream, J, KQ, Dx, rr);
    hipLaunchKernelGGL(k_convW, dim3(256), dim3(256), 0, stream, J, KQ, Dx, rr, state, outp);
}